// Round 17
// baseline (673.212 us; speedup 1.0000x reference)
//
#include <hip/hip_runtime.h>
#include <hip/hip_bf16.h>

#define NTOK 4096   // B*N
#define NN   512

typedef __attribute__((ext_vector_type(8))) short bf16x8;
typedef __attribute__((ext_vector_type(4))) float f32x4;
typedef __attribute__((ext_vector_type(4))) unsigned short u16x4;

__device__ __forceinline__ float bf16_to_f(unsigned short u) {
    unsigned int x = ((unsigned int)u) << 16;
    return __builtin_bit_cast(float, x);
}
__device__ __forceinline__ unsigned short f_to_bf16(float f) {
    unsigned int b = __builtin_bit_cast(unsigned int, f);
    return (unsigned short)((b + 0x7fff + ((b >> 16) & 1)) >> 16);
}
__device__ __forceinline__ bf16x8 pack8(float4 a, float4 b) {
    bf16x8 v;
    v[0]=(short)f_to_bf16(a.x); v[1]=(short)f_to_bf16(a.y);
    v[2]=(short)f_to_bf16(a.z); v[3]=(short)f_to_bf16(a.w);
    v[4]=(short)f_to_bf16(b.x); v[5]=(short)f_to_bf16(b.y);
    v[6]=(short)f_to_bf16(b.z); v[7]=(short)f_to_bf16(b.w);
    return v;
}

// ---------------------------------------------------------------------------
__global__ void detect_mask_kernel(const unsigned char* __restrict__ m, int* __restrict__ flag) {
    __shared__ int f;
    if (threadIdx.x == 0) f = 0;
    __syncthreads();
    int any = 0;
    for (int i = threadIdx.x; i < 4096; i += 256) {
        if ((i & 3) != 0 && m[i] != 0) any = 1;
    }
    if (any) atomicOr(&f, 1);
    __syncthreads();
    if (threadIdx.x == 0) *flag = f;   // 1 => byte mask, 0 => int32 mask
}

// ---------------------------------------------------------------------------
__global__ __launch_bounds__(256) void prep_rel16(
    const int* __restrict__ rel, const void* __restrict__ mask,
    const int* __restrict__ flag, short* __restrict__ rel16)
{
    const bool mbyte = (*flag != 0);
    const unsigned char* m8 = (const unsigned char*)mask;
    const int* m32 = (const int*)mask;
    const int i = (blockIdx.x * 256 + threadIdx.x) * 2;
    int2 rv = *(const int2*)(rel + i);
    int ok0, ok1;
    if (mbyte) { ok0 = m8[i]; ok1 = m8[i + 1]; }
    else       { ok0 = (m32[i] != 0); ok1 = (m32[i + 1] != 0); }
    short2 o;
    o.x = ok0 ? (short)rv.x : (short)-1;
    o.y = ok1 ? (short)rv.y : (short)-1;
    *(short2*)(rel16 + i) = o;
}

// ---------------------------------------------------------------------------
// Transpose-cast: out[n][k] = bf16(in[k][n] * sc), 256x256 weights (+Wout).
__global__ __launch_bounds__(256) void tcast256(
    const float* __restrict__ Wq, const float* __restrict__ Wk,
    const float* __restrict__ Wv, const float* __restrict__ Wo,
    const float* __restrict__ Wout, unsigned short* __restrict__ wt,
    int nL, float scale)
{
    const int z = blockIdx.z;
    const float* src; unsigned short* dst; float sc = 1.f;
    if (z >= nL * 4) {
        src = Wout; dst = wt + (size_t)nL * 786432;
    } else {
        const int l = z >> 2, which = z & 3;
        if      (which == 0) { src = Wq + (size_t)l * 65536; sc = scale; }
        else if (which == 1) { src = Wk + (size_t)l * 65536; }
        else if (which == 2) { src = Wv + (size_t)l * 65536; }
        else                 { src = Wo + (size_t)l * 65536; }
        dst = wt + (size_t)l * 786432 + which * 65536;
    }
    __shared__ float tile[32][33];
    const int t = threadIdx.x, tx = t & 31, ty = t >> 5;
    const int n0 = blockIdx.x * 32, k0 = blockIdx.y * 32;
#pragma unroll
    for (int p = 0; p < 4; ++p)
        tile[ty + p * 8][tx] = src[(size_t)(k0 + ty + p * 8) * 256 + n0 + tx];
    __syncthreads();
#pragma unroll
    for (int p = 0; p < 4; ++p)
        dst[(size_t)(n0 + ty + p * 8) * 256 + k0 + tx] = f_to_bf16(tile[tx][ty + p * 8] * sc);
}

// Generic transpose-cast for W1/W2 (z = layer index).
__global__ __launch_bounds__(256) void tcastKN(
    const float* __restrict__ in, unsigned short* __restrict__ out,
    int K, int N, long inStride, long outStride)
{
    in  += (size_t)blockIdx.z * inStride;
    out += (size_t)blockIdx.z * outStride;
    __shared__ float tile[32][33];
    const int t = threadIdx.x, tx = t & 31, ty = t >> 5;
    const int n0 = blockIdx.x * 32, k0 = blockIdx.y * 32;
#pragma unroll
    for (int p = 0; p < 4; ++p)
        tile[ty + p * 8][tx] = in[(size_t)(k0 + ty + p * 8) * N + n0 + tx];
    __syncthreads();
#pragma unroll
    for (int p = 0; p < 4; ++p)
        out[(size_t)(n0 + ty + p * 8) * K + k0 + tx] = f_to_bf16(tile[tx][ty + p * 8]);
}

// ---------------------------------------------------------------------------
__global__ __launch_bounds__(256) void embed_proj_kernel(
    const int* __restrict__ tok, const float* __restrict__ embed,
    const float* __restrict__ W_in, const float* __restrict__ b_in,
    float* __restrict__ x, unsigned short* __restrict__ xh)
{
    __shared__ float emb[8][304];
    __shared__ int tloc[8];
    const int t = threadIdx.x;
    const int r0 = blockIdx.x * 8;
    if (t < 8) tloc[t] = tok[r0 + t];
    __syncthreads();
    for (int i = t; i < 8 * 300; i += 256) {
        int r = i / 300, e = i - r * 300;
        emb[r][e] = embed[(size_t)tloc[r] * 300 + e];
    }
    __syncthreads();
    float acc[8] = {0.f,0.f,0.f,0.f,0.f,0.f,0.f,0.f};
    const int d = t;
    for (int e = 0; e < 300; ++e) {
        float w = W_in[e * 256 + d];
#pragma unroll
        for (int r = 0; r < 8; ++r) acc[r] += emb[r][e] * w;
    }
    const float bb = b_in[d];
#pragma unroll
    for (int r = 0; r < 8; ++r) {
        float o = acc[r] + bb;
        o = o > 0.f ? o : 0.f;
        x[(size_t)(r0 + r) * 256 + d] = o;
        xh[(size_t)(r0 + r) * 256 + d] = f_to_bf16(o);
    }
}

// ---------------------------------------------------------------------------
// bf16 GEMM, 64x64 tile, dbuf BK=32. A bf16 [M][K], WT bf16 [Nc][K].
__global__ __launch_bounds__(256) void gemm_bf16_64(
    const unsigned short* __restrict__ A, const unsigned short* __restrict__ WT,
    const float* __restrict__ bias, float* __restrict__ Cf, unsigned short* __restrict__ Ch,
    int M, int K, int Nc, int relu)
{
    __shared__ unsigned short As[2][64][40];
    __shared__ unsigned short Bs[2][64][40];
    const int t = threadIdx.x;
    const int lane = t & 63, w = t >> 6;
    const int g = lane >> 4, li = lane & 15;
    const int r0 = blockIdx.y * 64, c0 = blockIdx.x * 64;

    f32x4 acc[4];
#pragma unroll
    for (int i = 0; i < 4; ++i) acc[i] = (f32x4){0.f,0.f,0.f,0.f};

    const int arow = t >> 2, ad8 = (t & 3) * 8;

    bf16x8 a0 = *(const bf16x8*)(A  + (size_t)(r0 + arow) * K + ad8);
    bf16x8 b0 = *(const bf16x8*)(WT + (size_t)(c0 + arow) * K + ad8);

    const int nk = K >> 5;
    for (int ki = 0; ki < nk; ++ki) {
        const int cur = ki & 1;
        *(bf16x8*)&As[cur][arow][ad8] = a0;
        *(bf16x8*)&Bs[cur][arow][ad8] = b0;
        if (ki + 1 < nk) {
            const int k0 = (ki + 1) * 32;
            a0 = *(const bf16x8*)(A  + (size_t)(r0 + arow) * K + k0 + ad8);
            b0 = *(const bf16x8*)(WT + (size_t)(c0 + arow) * K + k0 + ad8);
        }
        __syncthreads();
        bf16x8 af = *(const bf16x8*)&As[cur][16 * w + li][g * 8];
#pragma unroll
        for (int sub = 0; sub < 4; ++sub) {
            bf16x8 bfr = *(const bf16x8*)&Bs[cur][16 * sub + li][g * 8];
            acc[sub] = __builtin_amdgcn_mfma_f32_16x16x32_bf16(af, bfr, acc[sub], 0, 0, 0);
        }
    }
#pragma unroll
    for (int sub = 0; sub < 4; ++sub) {
        int col = c0 + sub * 16 + li;
        float bv = bias ? bias[col] : 0.f;
#pragma unroll
        for (int r = 0; r < 4; ++r) {
            int row = r0 + 16 * w + g * 4 + r;
            float o = acc[sub][r] + bv;
            if (relu) o = fmaxf(o, 0.f);
            if (Ch) Ch[(size_t)row * Nc + col] = f_to_bf16(o);
            else    Cf[(size_t)row * Nc + col] = o;
        }
    }
}

// ---------------------------------------------------------------------------
// bf16 GEMM, 32x64 tile (N=256 GEMMs): doubles grid for occupancy.
__global__ __launch_bounds__(256) void gemm_bf16_32(
    const unsigned short* __restrict__ A, const unsigned short* __restrict__ WT,
    const float* __restrict__ bias, float* __restrict__ Cf, unsigned short* __restrict__ Ch,
    int M, int K, int Nc, int relu)
{
    __shared__ unsigned short As[2][32][40];
    __shared__ unsigned short Bs[2][64][40];
    const int t = threadIdx.x;
    const int lane = t & 63, w = t >> 6;
    const int g = lane >> 4, li = lane & 15;
    const int r0 = blockIdx.y * 32, c0 = blockIdx.x * 64;

    f32x4 acc[2];
    acc[0] = (f32x4){0.f,0.f,0.f,0.f};
    acc[1] = (f32x4){0.f,0.f,0.f,0.f};

    const int arow = t >> 3, a4 = (t & 7) * 4;
    const int bcol = t >> 2, bk8 = (t & 3) * 8;

    u16x4 a0 = *(const u16x4*)(A + (size_t)(r0 + arow) * K + a4);
    bf16x8 b0 = *(const bf16x8*)(WT + (size_t)(c0 + bcol) * K + bk8);

    const int nk = K >> 5;
    for (int ki = 0; ki < nk; ++ki) {
        const int cur = ki & 1;
        *(u16x4*)&As[cur][arow][a4] = a0;
        *(bf16x8*)&Bs[cur][bcol][bk8] = b0;
        if (ki + 1 < nk) {
            const int k0 = (ki + 1) * 32;
            a0 = *(const u16x4*)(A + (size_t)(r0 + arow) * K + k0 + a4);
            b0 = *(const bf16x8*)(WT + (size_t)(c0 + bcol) * K + k0 + bk8);
        }
        __syncthreads();
        bf16x8 af = *(const bf16x8*)&As[cur][16 * (w & 1) + li][g * 8];
#pragma unroll
        for (int sub = 0; sub < 2; ++sub) {
            bf16x8 bfr = *(const bf16x8*)&Bs[cur][(w >> 1) * 32 + sub * 16 + li][g * 8];
            acc[sub] = __builtin_amdgcn_mfma_f32_16x16x32_bf16(af, bfr, acc[sub], 0, 0, 0);
        }
    }
#pragma unroll
    for (int sub = 0; sub < 2; ++sub) {
        int col = c0 + (w >> 1) * 32 + sub * 16 + li;
        float bv = bias ? bias[col] : 0.f;
#pragma unroll
        for (int r = 0; r < 4; ++r) {
            int row = r0 + 16 * (w & 1) + g * 4 + r;
            float o = acc[sub][r] + bv;
            if (relu) o = fmaxf(o, 0.f);
            if (Ch) Ch[(size_t)row * Nc + col] = f_to_bf16(o);
            else    Cf[(size_t)row * Nc + col] = o;
        }
    }
}

// ---------------------------------------------------------------------------
// Wo GEMM with fused attention combine over 4 m-slices.
__global__ __launch_bounds__(256) void gemm_wo(
    const float* __restrict__ zpart, const float* __restrict__ smpart,
    const unsigned short* __restrict__ WT, float* __restrict__ Cf, int Nc)
{
    __shared__ unsigned short As[32][256];
    __shared__ unsigned short Bs[64][256];
    __shared__ float den[32][8];
    char* Ab = (char*)As; char* Bb = (char*)Bs;
    const int t = threadIdx.x;
    const int lane = t & 63, w = t >> 6;
    const int g = lane >> 4, li = lane & 15;
    const int r0 = blockIdx.y * 32, c0 = blockIdx.x * 64;

    {
        int row = t >> 3, h2 = t & 7;
        float s = 0.f;
#pragma unroll
        for (int sl = 0; sl < 4; ++sl)
            s += smpart[(size_t)sl * 32768 + (size_t)(r0 + row) * 8 + h2];
        den[row][h2] = 1.f / s;
    }
    __syncthreads();
#pragma unroll
    for (int j = 0; j < 4; ++j) {          // A panel 32x256 from zpart, normalized
        int idx = j * 256 + t;
        int row = idx >> 5;
        int k8 = (idx & 31) * 8;
        const float* z0 = zpart + (size_t)(r0 + row) * 256 + k8;
        float4 a0 = *(const float4*)z0, a1 = *(const float4*)(z0 + 4);
#pragma unroll
        for (int sl = 1; sl < 4; ++sl) {
            const float* zs = z0 + (size_t)sl * 1048576;
            float4 b0 = *(const float4*)zs, b1 = *(const float4*)(zs + 4);
            a0.x += b0.x; a0.y += b0.y; a0.z += b0.z; a0.w += b0.w;
            a1.x += b1.x; a1.y += b1.y; a1.z += b1.z; a1.w += b1.w;
        }
        float dv = den[row][k8 >> 5];
        a0.x *= dv; a0.y *= dv; a0.z *= dv; a0.w *= dv;
        a1.x *= dv; a1.y *= dv; a1.z *= dv; a1.w *= dv;
        int colb = (idx & 31) * 16;
        int sw = row * 512 + (colb ^ ((row & 7) << 4));
        *(bf16x8*)(Ab + sw) = pack8(a0, a1);
    }
#pragma unroll
    for (int j = 0; j < 8; ++j) {          // B panel 64x256
        int idx = j * 256 + t;
        int row = idx >> 5;
        int colb = (idx & 31) * 16;
        int sw = row * 512 + (colb ^ ((row & 7) << 4));
        *(bf16x8*)(Bb + sw) = *(const bf16x8*)(WT + (size_t)(c0 + row) * 256 + (idx & 31) * 8);
    }
    __syncthreads();
    f32x4 acc[2];
    acc[0] = (f32x4){0.f,0.f,0.f,0.f};
    acc[1] = (f32x4){0.f,0.f,0.f,0.f};
    const int arow = 16 * (w & 1) + li;
    const int xr = (li & 7) << 4;
#pragma unroll
    for (int ks = 0; ks < 8; ++ks) {
        const int kb = (g * 8 + ks * 32) * 2;
        bf16x8 af = *(const bf16x8*)(Ab + arow * 512 + (kb ^ xr));
#pragma unroll
        for (int sub = 0; sub < 2; ++sub) {
            const int brow = (w >> 1) * 32 + sub * 16 + li;
            bf16x8 bfr = *(const bf16x8*)(Bb + brow * 512 + (kb ^ xr));
            acc[sub] = __builtin_amdgcn_mfma_f32_16x16x32_bf16(af, bfr, acc[sub], 0, 0, 0);
        }
    }
#pragma unroll
    for (int sub = 0; sub < 2; ++sub) {
        int col = c0 + (w >> 1) * 32 + sub * 16 + li;
#pragma unroll
        for (int r = 0; r < 4; ++r) {
            int row = r0 + 16 * (w & 1) + g * 4 + r;
            Cf[(size_t)row * Nc + col] = acc[sub][r];
        }
    }
}

// ---------------------------------------------------------------------------
// qrk[b,h,n,rel] = q_n . relk[rel]  (q pre-scaled in Wq cast). Block=(chunk,h,b).
__global__ __launch_bounds__(256) void qrk_kernel(
    const unsigned short* __restrict__ qkvh, const float* __restrict__ relk_g,
    unsigned short* __restrict__ qrkg)
{
    const int n0 = blockIdx.x * 64, h = blockIdx.y, b = blockIdx.z;
    const int t = threadIdx.x, lane = t & 63, w = t >> 6;
    const int g = lane >> 4, li = lane & 15;
    const int qrow = 16 * w + g * 4;

    __shared__ unsigned short relk_s[100][40];
    for (int i = t; i < 400; i += 256) {
        int rr = i >> 2, d8 = (i & 3) * 8;
        const float* sp = relk_g + rr * 32 + d8;
        *(bf16x8*)&relk_s[rr][d8] = pack8(*(const float4*)sp, *(const float4*)(sp + 4));
    }
    bf16x8 qf = *(const bf16x8*)(qkvh + (size_t)(b * NN + n0 + 16 * w + li) * 768 + h * 32 + g * 8);
    __syncthreads();
#pragma unroll
    for (int rc = 0; rc < 7; ++rc) {
        bf16x8 bb = *(const bf16x8*)&relk_s[rc * 16 + li][g * 8];
        f32x4 s = __builtin_amdgcn_mfma_f32_16x16x32_bf16(qf, bb, (f32x4){0.f,0.f,0.f,0.f}, 0, 0, 0);
        int col = rc * 16 + li;
        if (col < 100) {
#pragma unroll
            for (int r = 0; r < 4; ++r)
                qrkg[((size_t)(b * 8 + h) * NN + n0 + qrow + r) * 100 + col] = f_to_bf16(s[r]);
        }
    }
}

// ---------------------------------------------------------------------------
// Attention, 512-thread blocks: 8 waves = 2 q-halves x 4 m-quarters (128 m,
// 4 tiles of 32). LDS 39.7KB -> 4 blocks/CU = 32 waves/CU (100% occupancy).
__global__ __launch_bounds__(512, 8) void attn_mfma(
    const unsigned short* __restrict__ qkvh,  // [4096][768] bf16, q pre-scaled
    const short* __restrict__ rel16,
    const unsigned short* __restrict__ qrkg,  // [64][512][100] bf16
    const float* __restrict__ relv_g,
    float* __restrict__ zpart,                // [4][4096][256]
    float* __restrict__ smpart)               // [4][4096][8]
{
    const int p = blockIdx.x;            // 0..1023
    const int cx = p & 7, k = p >> 3;    // k 0..127
    const int sg = cx * 16 + (k >> 3);   // (b, chunk32) slice, XCD-grouped
    const int h  = k & 7;
    const int b = sg >> 4, chunk = sg & 15;
    const int n0 = chunk * 32;

    const int t = threadIdx.x;           // 0..511
    const int lane = t & 63, w = t >> 6; // w 0..7
    const int qw = w & 1, mq = w >> 1;   // q-half, m-quarter
    const int g = lane >> 4, li = lane & 15;
    const int qrow = 16 * qw + g * 4;    // +r, 0..31
    const int mbase = mq * 128;

    __shared__ float wrel[32][100];            // 12800 B (shared, atomics)
    __shared__ unsigned short qrk_lds[32][100];// 6400 B
    __shared__ union {
        unsigned short relvT[32][136];         // 8704 B (epilogue)
        struct {
            unsigned short v_t[4][32][40];     // [mq][d][m] 10240 B (single-buf)
            unsigned short p_s[8][16][40];     // per-wave 10240 B
        } mn;                                  // 20480 B
    } u;                                       // total 39680 B -> 4 blocks/CU

    // prologue: zero wrel, bulk-stage qrk rows (32 x 50 dwords), load Q frag
    for (int i = t; i < 3200; i += 512) ((float*)wrel)[i] = 0.f;
    {
        const unsigned short* qsrc = qrkg + ((size_t)(b * 8 + h) * NN + n0) * 100;
        for (int i = t; i < 1600; i += 512) {
            int row = i / 50, off = (i - row * 50) * 2;
            *(unsigned int*)&qrk_lds[row][off] =
                *(const unsigned int*)(qsrc + (size_t)row * 100 + off);
        }
    }
    bf16x8 qf = *(const bf16x8*)(qkvh + (size_t)(b * NN + n0 + 16 * qw + li) * 768 + h * 32 + g * 8);

    const short* relrow[4];
#pragma unroll
    for (int r = 0; r < 4; ++r)
        relrow[r] = rel16 + ((size_t)b * NN + n0 + qrow + r) * NN;
    const int th = t & 127;              // id within the 2-wave m-quarter pair
    const int vm = th & 31, vdg = th >> 5;
    const size_t kRB = (size_t)(b * NN) * 768 + 256 + h * 32 + g * 8;
    const size_t vRB = (size_t)(b * NN) * 768 + 512 + h * 32 + vdg * 8;

    bf16x8 kbuf[2][2]; bf16x8 vbuf[2]; short rbuf[2][8];
#pragma unroll
    for (int i = 0; i < 8; ++i)
        rbuf[0][i] = relrow[i & 3][mbase + (i >> 2) * 16 + li];
    kbuf[0][0] = *(const bf16x8*)(qkvh + kRB + (size_t)(mbase + li) * 768);
    kbuf[0][1] = *(const bf16x8*)(qkvh + kRB + (size_t)(mbase + 16 + li) * 768);
    vbuf[0]    = *(const bf16x8*)(qkvh + vRB + (size_t)(mbase + vm) * 768);

    float smacc[4] = {0.f, 0.f, 0.f, 0.f};
    f32x4 zf[2];
    zf[0] = (f32x4){0.f,0.f,0.f,0.f};
    zf[1] = (f32x4){0.f,0.f,0.f,0.f};

    // main loop: 4 tiles of 32 m per m-quarter, two barriers per tile
#pragma unroll
    for (int tt = 0; tt < 4; ++tt) {
        const int cur = tt & 1, nxt = cur ^ 1;
        {   // write own quarter's V tile transposed [d][m]
            bf16x8 vv = vbuf[cur];
#pragma unroll
            for (int j = 0; j < 8; ++j)
                u.mn.v_t[mq][vdg * 8 + j][vm] = (unsigned short)vv[j];
        }
        if (tt + 1 < 4) {
            const int m0n = mbase + (tt + 1) * 32;
#pragma unroll
            for (int i = 0; i < 8; ++i)
                rbuf[nxt][i] = relrow[i & 3][m0n + (i >> 2) * 16 + li];
        }
        __syncthreads();
        bf16x8 kf0 = kbuf[cur][0], kf1 = kbuf[cur][1];
        if (tt + 1 < 4) {   // issue next K/V early (hide under compute)
            const int m0n = mbase + (tt + 1) * 32;
            kbuf[nxt][0] = *(const bf16x8*)(qkvh + kRB + (size_t)(m0n + li) * 768);
            kbuf[nxt][1] = *(const bf16x8*)(qkvh + kRB + (size_t)(m0n + 16 + li) * 768);
            vbuf[nxt]    = *(const bf16x8*)(qkvh + vRB + (size_t)(m0n + vm) * 768);
        }
        f32x4 s0 = __builtin_amdgcn_mfma_f32_16x16x32_bf16(qf, kf0, (f32x4){0.f,0.f,0.f,0.f}, 0, 0, 0);
        f32x4 s1 = __builtin_amdgcn_mfma_f32_16x16x32_bf16(qf, kf1, (f32x4){0.f,0.f,0.f,0.f}, 0, 0, 0);
        float pr[8];
#pragma unroll
        for (int i = 0; i < 8; ++i) {
            const int r = i & 3;
            const int rl = rbuf[cur][i];
            const float qadd = bf16_to_f(qrk_lds[qrow + r][rl < 0 ? 0 : rl]);
            const float sv = ((i >> 2) ? s1[r] : s0[r]) + qadd;
            float pv = 0.f;
            if (rl >= 0) {
                pv = __expf(fminf(sv, 50.f));
                atomicAdd(&wrel[qrow + r][rl], pv);
            }
            smacc[r] += pv;
            pr[i] = pv;
        }
#pragma unroll
        for (int i = 0; i < 8; ++i)
            u.mn.p_s[w][g * 4 + (i & 3)][(i >> 2) * 16 + li] = f_to_bf16(pr[i]);
        asm volatile("s_waitcnt lgkmcnt(0)" ::: "memory");
        __builtin_amdgcn_sched_barrier(0);
        bf16x8 pa = *(const bf16x8*)&u.mn.p_s[w][li][g * 8];
#pragma unroll
        for (int dc = 0; dc < 2; ++dc) {
            bf16x8 vb = *(const bf16x8*)&u.mn.v_t[mq][dc * 16 + li][g * 8];
            zf[dc] = __builtin_amdgcn_mfma_f32_16x16x32_bf16(pa, vb, zf[dc], 0, 0, 0);
        }
        __syncthreads();   // PV reads done before next tile overwrites v_t
    }

    // epilogue: stage relv^T (shared); wrel @ relv added by m-quarter 0 only
    for (int i = t; i < 32 * 36; i += 512) {
        int d = i / 36, c = 100 + (i - (i / 36) * 36);
        u.relvT[d][c] = 0;
    }
    for (int i = t; i < 400; i += 512) {
        int rr2 = i >> 2, d8 = (i & 3) * 8;
        const float* sp = relv_g + rr2 * 32 + d8;
        float4 s0 = *(const float4*)sp, s1 = *(const float4*)(sp + 4);
        u.relvT[d8 + 0][rr2] = f_to_bf16(s0.x);
        u.relvT[d8 + 1][rr2] = f_to_bf16(s0.y);
        u.relvT[d8 + 2][rr2] = f_to_bf16(s0.z);
        u.relvT[d8 + 3][rr2] = f_to_bf16(s0.w);
        u.relvT[d8 + 4][rr2] = f_to_bf16(s1.x);
        u.relvT[d8 + 5][rr2] = f_to_bf16(s1.y);
        u.relvT[d8 + 6][rr2] = f_to_bf16(s1.z);
        u.relvT[d8 + 7][rr2] = f_to_bf16(s1.w);
    }
    __syncthreads();
    if (mq == 0) {
#pragma unroll
        for (int kc = 0; kc < 4; ++kc) {
            const int kbase = kc * 32 + g * 8;
            const float* wp = &wrel[16 * qw + li][0];
            bf16x8 af;
#pragma unroll
            for (int j = 0; j < 8; ++j) {
                int id = kbase + j;
                float val = (id < 100) ? wp[id] : 0.f;
                af[j] = (short)f_to_bf16(val);
            }
#pragma unroll
            for (int dc = 0; dc < 2; ++dc) {
                bf16x8 vbr = *(const bf16x8*)&u.relvT[dc * 16 + li][kbase];
                zf[dc] = __builtin_amdgcn_mfma_f32_16x16x32_bf16(af, vbr, zf[dc], 0, 0, 0);
            }
        }
    }
#pragma unroll
    for (int r = 0; r < 4; ++r) {
        smacc[r] += __shfl_xor(smacc[r], 1, 64);
        smacc[r] += __shfl_xor(smacc[r], 2, 64);
        smacc[r] += __shfl_xor(smacc[r], 4, 64);
        smacc[r] += __shfl_xor(smacc[r], 8, 64);
    }
#pragma unroll
    for (int r = 0; r < 4; ++r) {
        const int row = b * NN + n0 + qrow + r;
        size_t ob = (size_t)mq * 1048576 + (size_t)row * 256 + h * 32;
#pragma unroll
        for (int dc = 0; dc < 2; ++dc)
            zpart[ob + dc * 16 + li] = zf[dc][r];
        if (li == 0)
            smpart[(size_t)mq * 32768 + (size_t)row * 8 + h] = smacc[r];
    }
}

// ---------------------------------------------------------------------------
__global__ __launch_bounds__(256) void ln_kernel(
    const float* __restrict__ xin, const float* __restrict__ y,
    const float* __restrict__ g, const float* __restrict__ bsh,
    float* __restrict__ xout, unsigned short* __restrict__ xh)
{
    const int t = threadIdx.x;
    const int w = t >> 6, lane = t & 63;
    const size_t row = (size_t)blockIdx.x * 4 + w;
    const float4 xv = *(const float4*)(xin + row * 256 + lane * 4);
    const float4 yv = *(const float4*)(y + row * 256 + lane * 4);
    float4 sv;
    sv.x = xv.x + yv.x; sv.y = xv.y + yv.y; sv.z = xv.z + yv.z; sv.w = xv.w + yv.w;
    float sum = sv.x + sv.y + sv.z + sv.w;
    float sq  = sv.x * sv.x + sv.y * sv.y + sv.z * sv.z + sv.w * sv.w;
#pragma unroll
    for (int off = 1; off < 64; off <<= 1) {
        sum += __shfl_xor(sum, off, 64);
        sq  += __shfl_xor(sq, off, 64);
    }
    const float mu = sum * (1.f / 256.f);
    const float var = sq * (1.f / 256.f) - mu * mu;
    const float rs = rsqrtf(var + 1e-5f);
    const float4 gv = *(const float4*)(g + lane * 4);
    const float4 bv = *(const float4*)(bsh + lane * 4);
    float4 o;
    o.x = (sv.x - mu) * rs * gv.x + bv.x;
    o.y = (sv.y - mu) * rs * gv.y + bv.y;
    o.z = (sv.z - mu) * rs * gv.z + bv.z;
    o.w = (sv.w - mu) * rs * gv.w + bv.w;
    *(float4*)(xout + row * 256 + lane * 4) = o;
    u16x4 oh;
    oh[0] = f_to_bf16(o.x); oh[1] = f_to_bf16(o.y);
    oh[2] = f_to_bf16(o.z); oh[3] = f_to_bf16(o.w);
    *(u16x4*)(xh + row * 256 + lane * 4) = oh;
}

// ---------------------------------------------------------------------------
extern "C" void kernel_launch(void* const* d_in, const int* in_sizes, int n_in,
                              void* d_out, int out_size, void* d_ws, size_t ws_size,
                              hipStream_t stream)
{
    (void)in_sizes; (void)n_in; (void)out_size;
    const int*   tok   = (const int*)d_in[0];
    const int*   rel   = (const int*)d_in[1];
    const void*  mask  = d_in[2];
    const float* embed = (const float*)d_in[3];
    const float* W_in  = (const float*)d_in[4];
    const float* b_in  = (const float*)d_in[5];
    const float* Wq    = (const float*)d_in[6];
    const float* Wk    = (const float*)d_in[7];
    const float* Wv    = (const float*)d_in[8];
    const float* Wo    = (const float*)d_in[9];
    const float* ln1g  = (const float*)d_in[10];
    const float* ln1b  = (const float*)d_in[11];
    const float* ln2g  = (const float*)d_in[12];
    const float* ln2b  = (const float*)d_in[13];
    const float* W1    = (const float*)d_in[14];
    const float* b1    = (const float*)d_in[15];
    const float* W2    = (const float*)d_in[16];
    const float* b2    = (const float*)d_in[17];
    const float* relk  = (const float*)d_in[18];
    const float* relv  = (const float*)d_in[19];
    const float* Wout  = (const float*)d_in[20];
    const float* bout  = (const float*)d_in[21];
    float* out = (float*)d_out;
    const float scale = 0.17677669529663687f;

    // Workspace layout (f32 offsets), sizes verified:
    //   x      [0,        1048576)   4096x256 f32
    //   xh     [1048576,  1572864)   4096x256 bf16
    //   zo     [1572864,  2621440)   4096x256 f32 (non-tierA rel16 home)
    //   qkvh   [2621440,  4194304)   4096x768 bf16
    //   zpart  [4194304,  8388608)   [4][4096][256] f32 (hbh aliases first 2M)
    //   smpart [8388608,  8519680)   [4][4096][8] f32
    //   qrkg   [8519680, 10158080)   64x512x100 bf16 = 1638400 f32
    //   flag   [10158080, 10158096)
    //   wt     [10158096, +1605632)  tierA: 4 layers + Wout -> ends 11763728
    //   rel16  [11763728, 13860624)  tierA: 4M shorts
    float* ws = (float*)d_ws;
    float*          x     = ws;
    unsigned short* xh    = (unsigned short*)(ws + 1048576);
    float*          zo    = ws + 1572864;
    unsigned short* qkvh  = (unsigned short*)(ws + 2621440);
    float*          zpart = ws + 4194304;
    unsigned short* hbh   = (unsigned short*)(ws + 4194304);
    float*          smpart= ws + 8388608;
    unsigned short* qrkg  = (unsigned short*)(ws + 8519680);
    int*            flag  = (int*)(ws + 10158080);
    unsigned short* wt    = (unsigned short*)(ws + 10158096);

    const size_t wsf = ws_size >> 2;
    const bool tierA = wsf >= 13860700;
    short* rel16 = tierA ? (short*)(ws + 11763728) : (short*)zo;

    detect_mask_kernel<<<1, 256, 0, stream>>>((const unsigned char*)mask, flag);
    embed_proj_kernel<<<512, 256, 0, stream>>>(tok, embed, W_in, b_in, x, xh);
    if (tierA) {
        prep_rel16<<<4096, 256, 0, stream>>>(rel, mask, flag, rel16);
        tcast256<<<dim3(8, 8, 17), 256, 0, stream>>>(Wq, Wk, Wv, Wo, Wout, wt, 4, scale);
        tcastKN<<<dim3(32, 8, 4), 256, 0, stream>>>(W1, wt + 262144, 256, 1024, 262144, 786432);
        tcastKN<<<dim3(8, 32, 4), 256, 0, stream>>>(W2, wt + 524288, 1024, 256, 262144, 786432);
    }

    for (int l = 0; l < 4; ++l) {
        unsigned short* wl = tierA ? wt + (size_t)l * 786432 : wt;
        if (!tierA) {
            prep_rel16<<<4096, 256, 0, stream>>>(rel, mask, flag, rel16);
            tcast256<<<dim3(8, 8, 4), 256, 0, stream>>>(
                Wq + (size_t)l * 65536, Wk + (size_t)l * 65536,
                Wv + (size_t)l * 65536, Wo + (size_t)l * 65536, Wout, wt, 1, scale);
            tcastKN<<<dim3(32, 8, 1), 256, 0, stream>>>(W1 + (size_t)l * 262144, wt + 262144, 256, 1024, 0, 0);
            tcastKN<<<dim3(8, 32, 1), 256, 0, stream>>>(W2 + (size_t)l * 262144, wt + 524288, 1024, 256, 0, 0);
        }
        // fused QKV (q pre-scaled): xh @ WqkvT -> qkvh bf16
        gemm_bf16_64<<<dim3(12, 64), 256, 0, stream>>>(xh, wl, nullptr, nullptr, qkvh,
                                                       NTOK, 256, 768, 0);
        qrk_kernel<<<dim3(8, 8, 8), 256, 0, stream>>>(qkvh, relk, qrkg);
        attn_mfma<<<1024, 512, 0, stream>>>(qkvh, rel16, qrkg, relv, zpart, smpart);
        // Wo GEMM with fused 4-slice combine/normalize
        gemm_wo<<<dim3(4, 128), 256, 0, stream>>>(zpart, smpart, wl + 196608, zo, 256);
        ln_kernel<<<1024, 256, 0, stream>>>(x, zo, ln1g + l * 256, ln1b + l * 256, x, xh);
        gemm_bf16_64<<<dim3(16, 64), 256, 0, stream>>>(xh, wl + 262144, b1 + l * 1024, nullptr, hbh,
                                                       NTOK, 256, 1024, 1);
        gemm_bf16_32<<<dim3(4, 128), 256, 0, stream>>>(hbh, wl + 524288, b2 + l * 256, zo, nullptr,
                                                       NTOK, 1024, 256, 0);
        ln_kernel<<<1024, 256, 0, stream>>>(x, zo, ln2g + l * 256, ln2b + l * 256, x, xh);
    }
    unsigned short* woutT = wt;
    if (tierA) {
        woutT = wt + (size_t)4 * 786432;
    } else {
        tcast256<<<dim3(8, 8, 1), 256, 0, stream>>>(Wq, Wk, Wv, Wo, Wout, wt, 0, scale);
    }
    gemm_bf16_32<<<dim3(4, 128), 256, 0, stream>>>(xh, woutT, bout, out, nullptr,
                                                   NTOK, 256, 256, 0);
}

// Round 18
// 644.953 us; speedup vs baseline: 1.0438x; 1.0438x over previous
//
#include <hip/hip_runtime.h>
#include <hip/hip_bf16.h>

#define NTOK 4096   // B*N
#define NN   512

typedef __attribute__((ext_vector_type(8))) short bf16x8;
typedef __attribute__((ext_vector_type(4))) float f32x4;
typedef __attribute__((ext_vector_type(4))) unsigned short u16x4;

__device__ __forceinline__ float bf16_to_f(unsigned short u) {
    unsigned int x = ((unsigned int)u) << 16;
    return __builtin_bit_cast(float, x);
}
__device__ __forceinline__ unsigned short f_to_bf16(float f) {
    unsigned int b = __builtin_bit_cast(unsigned int, f);
    return (unsigned short)((b + 0x7fff + ((b >> 16) & 1)) >> 16);
}
__device__ __forceinline__ bf16x8 pack8(float4 a, float4 b) {
    bf16x8 v;
    v[0]=(short)f_to_bf16(a.x); v[1]=(short)f_to_bf16(a.y);
    v[2]=(short)f_to_bf16(a.z); v[3]=(short)f_to_bf16(a.w);
    v[4]=(short)f_to_bf16(b.x); v[5]=(short)f_to_bf16(b.y);
    v[6]=(short)f_to_bf16(b.z); v[7]=(short)f_to_bf16(b.w);
    return v;
}

// ---------------------------------------------------------------------------
__global__ void detect_mask_kernel(const unsigned char* __restrict__ m, int* __restrict__ flag) {
    __shared__ int f;
    if (threadIdx.x == 0) f = 0;
    __syncthreads();
    int any = 0;
    for (int i = threadIdx.x; i < 4096; i += 256) {
        if ((i & 3) != 0 && m[i] != 0) any = 1;
    }
    if (any) atomicOr(&f, 1);
    __syncthreads();
    if (threadIdx.x == 0) *flag = f;   // 1 => byte mask, 0 => int32 mask
}

// ---------------------------------------------------------------------------
__global__ __launch_bounds__(256) void prep_rel16(
    const int* __restrict__ rel, const void* __restrict__ mask,
    const int* __restrict__ flag, short* __restrict__ rel16)
{
    const bool mbyte = (*flag != 0);
    const unsigned char* m8 = (const unsigned char*)mask;
    const int* m32 = (const int*)mask;
    const int i = (blockIdx.x * 256 + threadIdx.x) * 2;
    int2 rv = *(const int2*)(rel + i);
    int ok0, ok1;
    if (mbyte) { ok0 = m8[i]; ok1 = m8[i + 1]; }
    else       { ok0 = (m32[i] != 0); ok1 = (m32[i + 1] != 0); }
    short2 o;
    o.x = ok0 ? (short)rv.x : (short)-1;
    o.y = ok1 ? (short)rv.y : (short)-1;
    *(short2*)(rel16 + i) = o;
}

// ---------------------------------------------------------------------------
// Transpose-cast: out[n][k] = bf16(in[k][n] * sc), 256x256 weights (+Wout).
__global__ __launch_bounds__(256) void tcast256(
    const float* __restrict__ Wq, const float* __restrict__ Wk,
    const float* __restrict__ Wv, const float* __restrict__ Wo,
    const float* __restrict__ Wout, unsigned short* __restrict__ wt,
    int nL, float scale)
{
    const int z = blockIdx.z;
    const float* src; unsigned short* dst; float sc = 1.f;
    if (z >= nL * 4) {
        src = Wout; dst = wt + (size_t)nL * 786432;
    } else {
        const int l = z >> 2, which = z & 3;
        if      (which == 0) { src = Wq + (size_t)l * 65536; sc = scale; }
        else if (which == 1) { src = Wk + (size_t)l * 65536; }
        else if (which == 2) { src = Wv + (size_t)l * 65536; }
        else                 { src = Wo + (size_t)l * 65536; }
        dst = wt + (size_t)l * 786432 + which * 65536;
    }
    __shared__ float tile[32][33];
    const int t = threadIdx.x, tx = t & 31, ty = t >> 5;
    const int n0 = blockIdx.x * 32, k0 = blockIdx.y * 32;
#pragma unroll
    for (int p = 0; p < 4; ++p)
        tile[ty + p * 8][tx] = src[(size_t)(k0 + ty + p * 8) * 256 + n0 + tx];
    __syncthreads();
#pragma unroll
    for (int p = 0; p < 4; ++p)
        dst[(size_t)(n0 + ty + p * 8) * 256 + k0 + tx] = f_to_bf16(tile[tx][ty + p * 8] * sc);
}

// Generic transpose-cast for W1/W2 (z = layer index).
__global__ __launch_bounds__(256) void tcastKN(
    const float* __restrict__ in, unsigned short* __restrict__ out,
    int K, int N, long inStride, long outStride)
{
    in  += (size_t)blockIdx.z * inStride;
    out += (size_t)blockIdx.z * outStride;
    __shared__ float tile[32][33];
    const int t = threadIdx.x, tx = t & 31, ty = t >> 5;
    const int n0 = blockIdx.x * 32, k0 = blockIdx.y * 32;
#pragma unroll
    for (int p = 0; p < 4; ++p)
        tile[ty + p * 8][tx] = in[(size_t)(k0 + ty + p * 8) * N + n0 + tx];
    __syncthreads();
#pragma unroll
    for (int p = 0; p < 4; ++p)
        out[(size_t)(n0 + ty + p * 8) * K + k0 + tx] = f_to_bf16(tile[tx][ty + p * 8]);
}

// ---------------------------------------------------------------------------
__global__ __launch_bounds__(256) void embed_proj_kernel(
    const int* __restrict__ tok, const float* __restrict__ embed,
    const float* __restrict__ W_in, const float* __restrict__ b_in,
    float* __restrict__ x, unsigned short* __restrict__ xh)
{
    __shared__ float emb[8][304];
    __shared__ int tloc[8];
    const int t = threadIdx.x;
    const int r0 = blockIdx.x * 8;
    if (t < 8) tloc[t] = tok[r0 + t];
    __syncthreads();
    for (int i = t; i < 8 * 300; i += 256) {
        int r = i / 300, e = i - r * 300;
        emb[r][e] = embed[(size_t)tloc[r] * 300 + e];
    }
    __syncthreads();
    float acc[8] = {0.f,0.f,0.f,0.f,0.f,0.f,0.f,0.f};
    const int d = t;
    for (int e = 0; e < 300; ++e) {
        float w = W_in[e * 256 + d];
#pragma unroll
        for (int r = 0; r < 8; ++r) acc[r] += emb[r][e] * w;
    }
    const float bb = b_in[d];
#pragma unroll
    for (int r = 0; r < 8; ++r) {
        float o = acc[r] + bb;
        o = o > 0.f ? o : 0.f;
        x[(size_t)(r0 + r) * 256 + d] = o;
        xh[(size_t)(r0 + r) * 256 + d] = f_to_bf16(o);
    }
}

// ---------------------------------------------------------------------------
// bf16 GEMM, 64x64 tile, dbuf BK=32. A bf16 [M][K], WT bf16 [Nc][K].
__global__ __launch_bounds__(256) void gemm_bf16_64(
    const unsigned short* __restrict__ A, const unsigned short* __restrict__ WT,
    const float* __restrict__ bias, float* __restrict__ Cf, unsigned short* __restrict__ Ch,
    int M, int K, int Nc, int relu)
{
    __shared__ unsigned short As[2][64][40];
    __shared__ unsigned short Bs[2][64][40];
    const int t = threadIdx.x;
    const int lane = t & 63, w = t >> 6;
    const int g = lane >> 4, li = lane & 15;
    const int r0 = blockIdx.y * 64, c0 = blockIdx.x * 64;

    f32x4 acc[4];
#pragma unroll
    for (int i = 0; i < 4; ++i) acc[i] = (f32x4){0.f,0.f,0.f,0.f};

    const int arow = t >> 2, ad8 = (t & 3) * 8;

    bf16x8 a0 = *(const bf16x8*)(A  + (size_t)(r0 + arow) * K + ad8);
    bf16x8 b0 = *(const bf16x8*)(WT + (size_t)(c0 + arow) * K + ad8);

    const int nk = K >> 5;
    for (int ki = 0; ki < nk; ++ki) {
        const int cur = ki & 1;
        *(bf16x8*)&As[cur][arow][ad8] = a0;
        *(bf16x8*)&Bs[cur][arow][ad8] = b0;
        if (ki + 1 < nk) {
            const int k0 = (ki + 1) * 32;
            a0 = *(const bf16x8*)(A  + (size_t)(r0 + arow) * K + k0 + ad8);
            b0 = *(const bf16x8*)(WT + (size_t)(c0 + arow) * K + k0 + ad8);
        }
        __syncthreads();
        bf16x8 af = *(const bf16x8*)&As[cur][16 * w + li][g * 8];
#pragma unroll
        for (int sub = 0; sub < 4; ++sub) {
            bf16x8 bfr = *(const bf16x8*)&Bs[cur][16 * sub + li][g * 8];
            acc[sub] = __builtin_amdgcn_mfma_f32_16x16x32_bf16(af, bfr, acc[sub], 0, 0, 0);
        }
    }
#pragma unroll
    for (int sub = 0; sub < 4; ++sub) {
        int col = c0 + sub * 16 + li;
        float bv = bias ? bias[col] : 0.f;
#pragma unroll
        for (int r = 0; r < 4; ++r) {
            int row = r0 + 16 * w + g * 4 + r;
            float o = acc[sub][r] + bv;
            if (relu) o = fmaxf(o, 0.f);
            if (Ch) Ch[(size_t)row * Nc + col] = f_to_bf16(o);
            else    Cf[(size_t)row * Nc + col] = o;
        }
    }
}

// ---------------------------------------------------------------------------
// bf16 GEMM, 32x64 tile (N=256 GEMMs): doubles grid for occupancy.
__global__ __launch_bounds__(256) void gemm_bf16_32(
    const unsigned short* __restrict__ A, const unsigned short* __restrict__ WT,
    const float* __restrict__ bias, float* __restrict__ Cf, unsigned short* __restrict__ Ch,
    int M, int K, int Nc, int relu)
{
    __shared__ unsigned short As[2][32][40];
    __shared__ unsigned short Bs[2][64][40];
    const int t = threadIdx.x;
    const int lane = t & 63, w = t >> 6;
    const int g = lane >> 4, li = lane & 15;
    const int r0 = blockIdx.y * 32, c0 = blockIdx.x * 64;

    f32x4 acc[2];
    acc[0] = (f32x4){0.f,0.f,0.f,0.f};
    acc[1] = (f32x4){0.f,0.f,0.f,0.f};

    const int arow = t >> 3, a4 = (t & 7) * 4;
    const int bcol = t >> 2, bk8 = (t & 3) * 8;

    u16x4 a0 = *(const u16x4*)(A + (size_t)(r0 + arow) * K + a4);
    bf16x8 b0 = *(const bf16x8*)(WT + (size_t)(c0 + bcol) * K + bk8);

    const int nk = K >> 5;
    for (int ki = 0; ki < nk; ++ki) {
        const int cur = ki & 1;
        *(u16x4*)&As[cur][arow][a4] = a0;
        *(bf16x8*)&Bs[cur][bcol][bk8] = b0;
        if (ki + 1 < nk) {
            const int k0 = (ki + 1) * 32;
            a0 = *(const u16x4*)(A + (size_t)(r0 + arow) * K + k0 + a4);
            b0 = *(const bf16x8*)(WT + (size_t)(c0 + bcol) * K + k0 + bk8);
        }
        __syncthreads();
        bf16x8 af = *(const bf16x8*)&As[cur][16 * (w & 1) + li][g * 8];
#pragma unroll
        for (int sub = 0; sub < 2; ++sub) {
            bf16x8 bfr = *(const bf16x8*)&Bs[cur][(w >> 1) * 32 + sub * 16 + li][g * 8];
            acc[sub] = __builtin_amdgcn_mfma_f32_16x16x32_bf16(af, bfr, acc[sub], 0, 0, 0);
        }
    }
#pragma unroll
    for (int sub = 0; sub < 2; ++sub) {
        int col = c0 + (w >> 1) * 32 + sub * 16 + li;
        float bv = bias ? bias[col] : 0.f;
#pragma unroll
        for (int r = 0; r < 4; ++r) {
            int row = r0 + 16 * (w & 1) + g * 4 + r;
            float o = acc[sub][r] + bv;
            if (relu) o = fmaxf(o, 0.f);
            if (Ch) Ch[(size_t)row * Nc + col] = f_to_bf16(o);
            else    Cf[(size_t)row * Nc + col] = o;
        }
    }
}

// ---------------------------------------------------------------------------
// Wo GEMM with fused attention combine over 4 m-slices.
__global__ __launch_bounds__(256) void gemm_wo(
    const float* __restrict__ zpart, const float* __restrict__ smpart,
    const unsigned short* __restrict__ WT, float* __restrict__ Cf, int Nc)
{
    __shared__ unsigned short As[32][256];
    __shared__ unsigned short Bs[64][256];
    __shared__ float den[32][8];
    char* Ab = (char*)As; char* Bb = (char*)Bs;
    const int t = threadIdx.x;
    const int lane = t & 63, w = t >> 6;
    const int g = lane >> 4, li = lane & 15;
    const int r0 = blockIdx.y * 32, c0 = blockIdx.x * 64;

    {
        int row = t >> 3, h2 = t & 7;
        float s = 0.f;
#pragma unroll
        for (int sl = 0; sl < 4; ++sl)
            s += smpart[(size_t)sl * 32768 + (size_t)(r0 + row) * 8 + h2];
        den[row][h2] = 1.f / s;
    }
    __syncthreads();
#pragma unroll
    for (int j = 0; j < 4; ++j) {          // A panel 32x256 from zpart, normalized
        int idx = j * 256 + t;
        int row = idx >> 5;
        int k8 = (idx & 31) * 8;
        const float* z0 = zpart + (size_t)(r0 + row) * 256 + k8;
        float4 a0 = *(const float4*)z0, a1 = *(const float4*)(z0 + 4);
#pragma unroll
        for (int sl = 1; sl < 4; ++sl) {
            const float* zs = z0 + (size_t)sl * 1048576;
            float4 b0 = *(const float4*)zs, b1 = *(const float4*)(zs + 4);
            a0.x += b0.x; a0.y += b0.y; a0.z += b0.z; a0.w += b0.w;
            a1.x += b1.x; a1.y += b1.y; a1.z += b1.z; a1.w += b1.w;
        }
        float dv = den[row][k8 >> 5];
        a0.x *= dv; a0.y *= dv; a0.z *= dv; a0.w *= dv;
        a1.x *= dv; a1.y *= dv; a1.z *= dv; a1.w *= dv;
        int colb = (idx & 31) * 16;
        int sw = row * 512 + (colb ^ ((row & 7) << 4));
        *(bf16x8*)(Ab + sw) = pack8(a0, a1);
    }
#pragma unroll
    for (int j = 0; j < 8; ++j) {          // B panel 64x256
        int idx = j * 256 + t;
        int row = idx >> 5;
        int colb = (idx & 31) * 16;
        int sw = row * 512 + (colb ^ ((row & 7) << 4));
        *(bf16x8*)(Bb + sw) = *(const bf16x8*)(WT + (size_t)(c0 + row) * 256 + (idx & 31) * 8);
    }
    __syncthreads();
    f32x4 acc[2];
    acc[0] = (f32x4){0.f,0.f,0.f,0.f};
    acc[1] = (f32x4){0.f,0.f,0.f,0.f};
    const int arow = 16 * (w & 1) + li;
    const int xr = (li & 7) << 4;
#pragma unroll
    for (int ks = 0; ks < 8; ++ks) {
        const int kb = (g * 8 + ks * 32) * 2;
        bf16x8 af = *(const bf16x8*)(Ab + arow * 512 + (kb ^ xr));
#pragma unroll
        for (int sub = 0; sub < 2; ++sub) {
            const int brow = (w >> 1) * 32 + sub * 16 + li;
            bf16x8 bfr = *(const bf16x8*)(Bb + brow * 512 + (kb ^ xr));
            acc[sub] = __builtin_amdgcn_mfma_f32_16x16x32_bf16(af, bfr, acc[sub], 0, 0, 0);
        }
    }
#pragma unroll
    for (int sub = 0; sub < 2; ++sub) {
        int col = c0 + (w >> 1) * 32 + sub * 16 + li;
#pragma unroll
        for (int r = 0; r < 4; ++r) {
            int row = r0 + 16 * (w & 1) + g * 4 + r;
            Cf[(size_t)row * Nc + col] = acc[sub][r];
        }
    }
}

// ---------------------------------------------------------------------------
// qrk[b,h,n,rel] = q_n . relk[rel]  (q pre-scaled in Wq cast). Block=(chunk,h,b).
__global__ __launch_bounds__(256) void qrk_kernel(
    const unsigned short* __restrict__ qkvh, const float* __restrict__ relk_g,
    unsigned short* __restrict__ qrkg)
{
    const int n0 = blockIdx.x * 64, h = blockIdx.y, b = blockIdx.z;
    const int t = threadIdx.x, lane = t & 63, w = t >> 6;
    const int g = lane >> 4, li = lane & 15;
    const int qrow = 16 * w + g * 4;

    __shared__ unsigned short relk_s[100][40];
    for (int i = t; i < 400; i += 256) {
        int rr = i >> 2, d8 = (i & 3) * 8;
        const float* sp = relk_g + rr * 32 + d8;
        *(bf16x8*)&relk_s[rr][d8] = pack8(*(const float4*)sp, *(const float4*)(sp + 4));
    }
    bf16x8 qf = *(const bf16x8*)(qkvh + (size_t)(b * NN + n0 + 16 * w + li) * 768 + h * 32 + g * 8);
    __syncthreads();
#pragma unroll
    for (int rc = 0; rc < 7; ++rc) {
        bf16x8 bb = *(const bf16x8*)&relk_s[rc * 16 + li][g * 8];
        f32x4 s = __builtin_amdgcn_mfma_f32_16x16x32_bf16(qf, bb, (f32x4){0.f,0.f,0.f,0.f}, 0, 0, 0);
        int col = rc * 16 + li;
        if (col < 100) {
#pragma unroll
            for (int r = 0; r < 4; ++r)
                qrkg[((size_t)(b * 8 + h) * NN + n0 + qrow + r) * 100 + col] = f_to_bf16(s[r]);
        }
    }
}

// ---------------------------------------------------------------------------
// Attention, 512-thread blocks: 8 waves = 2 q-halves x 4 m-quarters.
// NO min-waves bound: compiler free to allocate ~64 VGPR (no spills);
// LDS 39.7KB allows 4 blocks/CU = 32 waves/CU if VGPR <= 64.
__global__ __launch_bounds__(512) void attn_mfma(
    const unsigned short* __restrict__ qkvh,  // [4096][768] bf16, q pre-scaled
    const short* __restrict__ rel16,
    const unsigned short* __restrict__ qrkg,  // [64][512][100] bf16
    const float* __restrict__ relv_g,
    float* __restrict__ zpart,                // [4][4096][256]
    float* __restrict__ smpart)               // [4][4096][8]
{
    const int p = blockIdx.x;            // 0..1023
    const int cx = p & 7, k = p >> 3;    // k 0..127
    const int sg = cx * 16 + (k >> 3);   // (b, chunk32) slice, XCD-grouped
    const int h  = k & 7;
    const int b = sg >> 4, chunk = sg & 15;
    const int n0 = chunk * 32;

    const int t = threadIdx.x;           // 0..511
    const int lane = t & 63, w = t >> 6; // w 0..7
    const int qw = w & 1, mq = w >> 1;   // q-half, m-quarter
    const int g = lane >> 4, li = lane & 15;
    const int qrow = 16 * qw + g * 4;    // +r, 0..31
    const int mbase = mq * 128;

    __shared__ float wrel[32][100];            // 12800 B (shared, atomics)
    __shared__ unsigned short qrk_lds[32][100];// 6400 B
    __shared__ union {
        unsigned short relvT[32][136];         // 8704 B (epilogue)
        struct {
            unsigned short v_t[4][32][40];     // [mq][d][m] 10240 B (single-buf)
            unsigned short p_s[8][16][40];     // per-wave 10240 B
        } mn;                                  // 20480 B
    } u;                                       // total 39680 B -> 4 blocks/CU

    // prologue: zero wrel, bulk-stage qrk rows (32 x 50 dwords), load Q frag
    for (int i = t; i < 3200; i += 512) ((float*)wrel)[i] = 0.f;
    {
        const unsigned short* qsrc = qrkg + ((size_t)(b * 8 + h) * NN + n0) * 100;
        for (int i = t; i < 1600; i += 512) {
            int row = i / 50, off = (i - row * 50) * 2;
            *(unsigned int*)&qrk_lds[row][off] =
                *(const unsigned int*)(qsrc + (size_t)row * 100 + off);
        }
    }
    bf16x8 qf = *(const bf16x8*)(qkvh + (size_t)(b * NN + n0 + 16 * qw + li) * 768 + h * 32 + g * 8);

    const short* relrow[4];
#pragma unroll
    for (int r = 0; r < 4; ++r)
        relrow[r] = rel16 + ((size_t)b * NN + n0 + qrow + r) * NN;
    const int th = t & 127;              // id within the 2-wave m-quarter pair
    const int vm = th & 31, vdg = th >> 5;
    const size_t kRB = (size_t)(b * NN) * 768 + 256 + h * 32 + g * 8;
    const size_t vRB = (size_t)(b * NN) * 768 + 512 + h * 32 + vdg * 8;

    bf16x8 kbuf[2][2]; bf16x8 vbuf[2]; short rbuf[2][8];
#pragma unroll
    for (int i = 0; i < 8; ++i)
        rbuf[0][i] = relrow[i & 3][mbase + (i >> 2) * 16 + li];
    kbuf[0][0] = *(const bf16x8*)(qkvh + kRB + (size_t)(mbase + li) * 768);
    kbuf[0][1] = *(const bf16x8*)(qkvh + kRB + (size_t)(mbase + 16 + li) * 768);
    vbuf[0]    = *(const bf16x8*)(qkvh + vRB + (size_t)(mbase + vm) * 768);

    float smacc[4] = {0.f, 0.f, 0.f, 0.f};
    f32x4 zf[2];
    zf[0] = (f32x4){0.f,0.f,0.f,0.f};
    zf[1] = (f32x4){0.f,0.f,0.f,0.f};

    // main loop: 4 tiles of 32 m per m-quarter, two barriers per tile
#pragma unroll
    for (int tt = 0; tt < 4; ++tt) {
        const int cur = tt & 1, nxt = cur ^ 1;
        {   // write own quarter's V tile transposed [d][m]
            bf16x8 vv = vbuf[cur];
#pragma unroll
            for (int j = 0; j < 8; ++j)
                u.mn.v_t[mq][vdg * 8 + j][vm] = (unsigned short)vv[j];
        }
        if (tt + 1 < 4) {
            const int m0n = mbase + (tt + 1) * 32;
#pragma unroll
            for (int i = 0; i < 8; ++i)
                rbuf[nxt][i] = relrow[i & 3][m0n + (i >> 2) * 16 + li];
        }
        __syncthreads();
        bf16x8 kf0 = kbuf[cur][0], kf1 = kbuf[cur][1];
        if (tt + 1 < 4) {   // issue next K/V early (hide under compute)
            const int m0n = mbase + (tt + 1) * 32;
            kbuf[nxt][0] = *(const bf16x8*)(qkvh + kRB + (size_t)(m0n + li) * 768);
            kbuf[nxt][1] = *(const bf16x8*)(qkvh + kRB + (size_t)(m0n + 16 + li) * 768);
            vbuf[nxt]    = *(const bf16x8*)(qkvh + vRB + (size_t)(m0n + vm) * 768);
        }
        f32x4 s0 = __builtin_amdgcn_mfma_f32_16x16x32_bf16(qf, kf0, (f32x4){0.f,0.f,0.f,0.f}, 0, 0, 0);
        f32x4 s1 = __builtin_amdgcn_mfma_f32_16x16x32_bf16(qf, kf1, (f32x4){0.f,0.f,0.f,0.f}, 0, 0, 0);
        float pr[8];
#pragma unroll
        for (int i = 0; i < 8; ++i) {
            const int r = i & 3;
            const int rl = rbuf[cur][i];
            const float qadd = bf16_to_f(qrk_lds[qrow + r][rl < 0 ? 0 : rl]);
            const float sv = ((i >> 2) ? s1[r] : s0[r]) + qadd;
            float pv = 0.f;
            if (rl >= 0) {
                pv = __expf(fminf(sv, 50.f));
                atomicAdd(&wrel[qrow + r][rl], pv);
            }
            smacc[r] += pv;
            pr[i] = pv;
        }
#pragma unroll
        for (int i = 0; i < 8; ++i)
            u.mn.p_s[w][g * 4 + (i & 3)][(i >> 2) * 16 + li] = f_to_bf16(pr[i]);
        asm volatile("s_waitcnt lgkmcnt(0)" ::: "memory");
        __builtin_amdgcn_sched_barrier(0);
        bf16x8 pa = *(const bf16x8*)&u.mn.p_s[w][li][g * 8];
#pragma unroll
        for (int dc = 0; dc < 2; ++dc) {
            bf16x8 vb = *(const bf16x8*)&u.mn.v_t[mq][dc * 16 + li][g * 8];
            zf[dc] = __builtin_amdgcn_mfma_f32_16x16x32_bf16(pa, vb, zf[dc], 0, 0, 0);
        }
        __syncthreads();   // PV reads done before next tile overwrites v_t
    }

    // epilogue: stage relv^T (shared); wrel @ relv added by m-quarter 0 only
    for (int i = t; i < 32 * 36; i += 512) {
        int d = i / 36, c = 100 + (i - (i / 36) * 36);
        u.relvT[d][c] = 0;
    }
    for (int i = t; i < 400; i += 512) {
        int rr2 = i >> 2, d8 = (i & 3) * 8;
        const float* sp = relv_g + rr2 * 32 + d8;
        float4 s0 = *(const float4*)sp, s1 = *(const float4*)(sp + 4);
        u.relvT[d8 + 0][rr2] = f_to_bf16(s0.x);
        u.relvT[d8 + 1][rr2] = f_to_bf16(s0.y);
        u.relvT[d8 + 2][rr2] = f_to_bf16(s0.z);
        u.relvT[d8 + 3][rr2] = f_to_bf16(s0.w);
        u.relvT[d8 + 4][rr2] = f_to_bf16(s1.x);
        u.relvT[d8 + 5][rr2] = f_to_bf16(s1.y);
        u.relvT[d8 + 6][rr2] = f_to_bf16(s1.z);
        u.relvT[d8 + 7][rr2] = f_to_bf16(s1.w);
    }
    __syncthreads();
    if (mq == 0) {
#pragma unroll
        for (int kc = 0; kc < 4; ++kc) {
            const int kbase = kc * 32 + g * 8;
            const float* wp = &wrel[16 * qw + li][0];
            bf16x8 af;
#pragma unroll
            for (int j = 0; j < 8; ++j) {
                int id = kbase + j;
                float val = (id < 100) ? wp[id] : 0.f;
                af[j] = (short)f_to_bf16(val);
            }
#pragma unroll
            for (int dc = 0; dc < 2; ++dc) {
                bf16x8 vbr = *(const bf16x8*)&u.relvT[dc * 16 + li][kbase];
                zf[dc] = __builtin_amdgcn_mfma_f32_16x16x32_bf16(af, vbr, zf[dc], 0, 0, 0);
            }
        }
    }
#pragma unroll
    for (int r = 0; r < 4; ++r) {
        smacc[r] += __shfl_xor(smacc[r], 1, 64);
        smacc[r] += __shfl_xor(smacc[r], 2, 64);
        smacc[r] += __shfl_xor(smacc[r], 4, 64);
        smacc[r] += __shfl_xor(smacc[r], 8, 64);
    }
#pragma unroll
    for (int r = 0; r < 4; ++r) {
        const int row = b * NN + n0 + qrow + r;
        size_t ob = (size_t)mq * 1048576 + (size_t)row * 256 + h * 32;
#pragma unroll
        for (int dc = 0; dc < 2; ++dc)
            zpart[ob + dc * 16 + li] = zf[dc][r];
        if (li == 0)
            smpart[(size_t)mq * 32768 + (size_t)row * 8 + h] = smacc[r];
    }
}

// ---------------------------------------------------------------------------
__global__ __launch_bounds__(256) void ln_kernel(
    const float* __restrict__ xin, const float* __restrict__ y,
    const float* __restrict__ g, const float* __restrict__ bsh,
    float* __restrict__ xout, unsigned short* __restrict__ xh)
{
    const int t = threadIdx.x;
    const int w = t >> 6, lane = t & 63;
    const size_t row = (size_t)blockIdx.x * 4 + w;
    const float4 xv = *(const float4*)(xin + row * 256 + lane * 4);
    const float4 yv = *(const float4*)(y + row * 256 + lane * 4);
    float4 sv;
    sv.x = xv.x + yv.x; sv.y = xv.y + yv.y; sv.z = xv.z + yv.z; sv.w = xv.w + yv.w;
    float sum = sv.x + sv.y + sv.z + sv.w;
    float sq  = sv.x * sv.x + sv.y * sv.y + sv.z * sv.z + sv.w * sv.w;
#pragma unroll
    for (int off = 1; off < 64; off <<= 1) {
        sum += __shfl_xor(sum, off, 64);
        sq  += __shfl_xor(sq, off, 64);
    }
    const float mu = sum * (1.f / 256.f);
    const float var = sq * (1.f / 256.f) - mu * mu;
    const float rs = rsqrtf(var + 1e-5f);
    const float4 gv = *(const float4*)(g + lane * 4);
    const float4 bv = *(const float4*)(bsh + lane * 4);
    float4 o;
    o.x = (sv.x - mu) * rs * gv.x + bv.x;
    o.y = (sv.y - mu) * rs * gv.y + bv.y;
    o.z = (sv.z - mu) * rs * gv.z + bv.z;
    o.w = (sv.w - mu) * rs * gv.w + bv.w;
    *(float4*)(xout + row * 256 + lane * 4) = o;
    u16x4 oh;
    oh[0] = f_to_bf16(o.x); oh[1] = f_to_bf16(o.y);
    oh[2] = f_to_bf16(o.z); oh[3] = f_to_bf16(o.w);
    *(u16x4*)(xh + row * 256 + lane * 4) = oh;
}

// ---------------------------------------------------------------------------
extern "C" void kernel_launch(void* const* d_in, const int* in_sizes, int n_in,
                              void* d_out, int out_size, void* d_ws, size_t ws_size,
                              hipStream_t stream)
{
    (void)in_sizes; (void)n_in; (void)out_size;
    const int*   tok   = (const int*)d_in[0];
    const int*   rel   = (const int*)d_in[1];
    const void*  mask  = d_in[2];
    const float* embed = (const float*)d_in[3];
    const float* W_in  = (const float*)d_in[4];
    const float* b_in  = (const float*)d_in[5];
    const float* Wq    = (const float*)d_in[6];
    const float* Wk    = (const float*)d_in[7];
    const float* Wv    = (const float*)d_in[8];
    const float* Wo    = (const float*)d_in[9];
    const float* ln1g  = (const float*)d_in[10];
    const float* ln1b  = (const float*)d_in[11];
    const float* ln2g  = (const float*)d_in[12];
    const float* ln2b  = (const float*)d_in[13];
    const float* W1    = (const float*)d_in[14];
    const float* b1    = (const float*)d_in[15];
    const float* W2    = (const float*)d_in[16];
    const float* b2    = (const float*)d_in[17];
    const float* relk  = (const float*)d_in[18];
    const float* relv  = (const float*)d_in[19];
    const float* Wout  = (const float*)d_in[20];
    const float* bout  = (const float*)d_in[21];
    float* out = (float*)d_out;
    const float scale = 0.17677669529663687f;

    float* ws = (float*)d_ws;
    float*          x     = ws;
    unsigned short* xh    = (unsigned short*)(ws + 1048576);
    float*          zo    = ws + 1572864;
    unsigned short* qkvh  = (unsigned short*)(ws + 2621440);
    float*          zpart = ws + 4194304;
    unsigned short* hbh   = (unsigned short*)(ws + 4194304);
    float*          smpart= ws + 8388608;
    unsigned short* qrkg  = (unsigned short*)(ws + 8519680);
    int*            flag  = (int*)(ws + 10158080);
    unsigned short* wt    = (unsigned short*)(ws + 10158096);

    const size_t wsf = ws_size >> 2;
    const bool tierA = wsf >= 13860700;
    short* rel16 = tierA ? (short*)(ws + 11763728) : (short*)zo;

    detect_mask_kernel<<<1, 256, 0, stream>>>((const unsigned char*)mask, flag);
    embed_proj_kernel<<<512, 256, 0, stream>>>(tok, embed, W_in, b_in, x, xh);
    if (tierA) {
        prep_rel16<<<4096, 256, 0, stream>>>(rel, mask, flag, rel16);
        tcast256<<<dim3(8, 8, 17), 256, 0, stream>>>(Wq, Wk, Wv, Wo, Wout, wt, 4, scale);
        tcastKN<<<dim3(32, 8, 4), 256, 0, stream>>>(W1, wt + 262144, 256, 1024, 262144, 786432);
        tcastKN<<<dim3(8, 32, 4), 256, 0, stream>>>(W2, wt + 524288, 1024, 256, 262144, 786432);
    }

    for (int l = 0; l < 4; ++l) {
        unsigned short* wl = tierA ? wt + (size_t)l * 786432 : wt;
        if (!tierA) {
            prep_rel16<<<4096, 256, 0, stream>>>(rel, mask, flag, rel16);
            tcast256<<<dim3(8, 8, 4), 256, 0, stream>>>(
                Wq + (size_t)l * 65536, Wk + (size_t)l * 65536,
                Wv + (size_t)l * 65536, Wo + (size_t)l * 65536, Wout, wt, 1, scale);
            tcastKN<<<dim3(32, 8, 1), 256, 0, stream>>>(W1 + (size_t)l * 262144, wt + 262144, 256, 1024, 0, 0);
            tcastKN<<<dim3(8, 32, 1), 256, 0, stream>>>(W2 + (size_t)l * 262144, wt + 524288, 1024, 256, 0, 0);
        }
        // fused QKV (q pre-scaled): xh @ WqkvT -> qkvh bf16
        gemm_bf16_64<<<dim3(12, 64), 256, 0, stream>>>(xh, wl, nullptr, nullptr, qkvh,
                                                       NTOK, 256, 768, 0);
        qrk_kernel<<<dim3(8, 8, 8), 256, 0, stream>>>(qkvh, relk, qrkg);
        attn_mfma<<<1024, 512, 0, stream>>>(qkvh, rel16, qrkg, relv, zpart, smpart);
        // Wo GEMM with fused 4-slice combine/normalize
        gemm_wo<<<dim3(4, 128), 256, 0, stream>>>(zpart, smpart, wl + 196608, zo, 256);
        ln_kernel<<<1024, 256, 0, stream>>>(x, zo, ln1g + l * 256, ln1b + l * 256, x, xh);
        gemm_bf16_64<<<dim3(16, 64), 256, 0, stream>>>(xh, wl + 262144, b1 + l * 1024, nullptr, hbh,
                                                       NTOK, 256, 1024, 1);
        gemm_bf16_32<<<dim3(4, 128), 256, 0, stream>>>(hbh, wl + 524288, b2 + l * 256, zo, nullptr,
                                                       NTOK, 1024, 256, 0);
        ln_kernel<<<1024, 256, 0, stream>>>(x, zo, ln2g + l * 256, ln2b + l * 256, x, xh);
    }
    unsigned short* woutT = wt;
    if (tierA) {
        woutT = wt + (size_t)4 * 786432;
    } else {
        tcast256<<<dim3(8, 8, 1), 256, 0, stream>>>(Wq, Wk, Wv, Wo, Wout, wt, 0, scale);
    }
    gemm_bf16_32<<<dim3(4, 128), 256, 0, stream>>>(xh, woutT, bout, out, nullptr,
                                                   NTOK, 256, 256, 0);
}

// Round 19
// 619.226 us; speedup vs baseline: 1.0872x; 1.0415x over previous
//
#include <hip/hip_runtime.h>
#include <hip/hip_bf16.h>

#define NTOK 4096   // B*N
#define NN   512

typedef __attribute__((ext_vector_type(8))) short bf16x8;
typedef __attribute__((ext_vector_type(4))) float f32x4;
typedef __attribute__((ext_vector_type(4))) unsigned short u16x4;

__device__ __forceinline__ float bf16_to_f(unsigned short u) {
    unsigned int x = ((unsigned int)u) << 16;
    return __builtin_bit_cast(float, x);
}
__device__ __forceinline__ unsigned short f_to_bf16(float f) {
    unsigned int b = __builtin_bit_cast(unsigned int, f);
    return (unsigned short)((b + 0x7fff + ((b >> 16) & 1)) >> 16);
}
__device__ __forceinline__ bf16x8 pack8(float4 a, float4 b) {
    bf16x8 v;
    v[0]=(short)f_to_bf16(a.x); v[1]=(short)f_to_bf16(a.y);
    v[2]=(short)f_to_bf16(a.z); v[3]=(short)f_to_bf16(a.w);
    v[4]=(short)f_to_bf16(b.x); v[5]=(short)f_to_bf16(b.y);
    v[6]=(short)f_to_bf16(b.z); v[7]=(short)f_to_bf16(b.w);
    return v;
}

// ---------------------------------------------------------------------------
__global__ void detect_mask_kernel(const unsigned char* __restrict__ m, int* __restrict__ flag) {
    __shared__ int f;
    if (threadIdx.x == 0) f = 0;
    __syncthreads();
    int any = 0;
    for (int i = threadIdx.x; i < 4096; i += 256) {
        if ((i & 3) != 0 && m[i] != 0) any = 1;
    }
    if (any) atomicOr(&f, 1);
    __syncthreads();
    if (threadIdx.x == 0) *flag = f;   // 1 => byte mask, 0 => int32 mask
}

// ---------------------------------------------------------------------------
__global__ __launch_bounds__(256) void prep_rel16(
    const int* __restrict__ rel, const void* __restrict__ mask,
    const int* __restrict__ flag, short* __restrict__ rel16)
{
    const bool mbyte = (*flag != 0);
    const unsigned char* m8 = (const unsigned char*)mask;
    const int* m32 = (const int*)mask;
    const int i = (blockIdx.x * 256 + threadIdx.x) * 2;
    int2 rv = *(const int2*)(rel + i);
    int ok0, ok1;
    if (mbyte) { ok0 = m8[i]; ok1 = m8[i + 1]; }
    else       { ok0 = (m32[i] != 0); ok1 = (m32[i + 1] != 0); }
    short2 o;
    o.x = ok0 ? (short)rv.x : (short)-1;
    o.y = ok1 ? (short)rv.y : (short)-1;
    *(short2*)(rel16 + i) = o;
}

// ---------------------------------------------------------------------------
// Transpose-cast: out[n][k] = bf16(in[k][n] * sc), 256x256 weights (+Wout).
__global__ __launch_bounds__(256) void tcast256(
    const float* __restrict__ Wq, const float* __restrict__ Wk,
    const float* __restrict__ Wv, const float* __restrict__ Wo,
    const float* __restrict__ Wout, unsigned short* __restrict__ wt,
    int nL, float scale)
{
    const int z = blockIdx.z;
    const float* src; unsigned short* dst; float sc = 1.f;
    if (z >= nL * 4) {
        src = Wout; dst = wt + (size_t)nL * 786432;
    } else {
        const int l = z >> 2, which = z & 3;
        if      (which == 0) { src = Wq + (size_t)l * 65536; sc = scale; }
        else if (which == 1) { src = Wk + (size_t)l * 65536; }
        else if (which == 2) { src = Wv + (size_t)l * 65536; }
        else                 { src = Wo + (size_t)l * 65536; }
        dst = wt + (size_t)l * 786432 + which * 65536;
    }
    __shared__ float tile[32][33];
    const int t = threadIdx.x, tx = t & 31, ty = t >> 5;
    const int n0 = blockIdx.x * 32, k0 = blockIdx.y * 32;
#pragma unroll
    for (int p = 0; p < 4; ++p)
        tile[ty + p * 8][tx] = src[(size_t)(k0 + ty + p * 8) * 256 + n0 + tx];
    __syncthreads();
#pragma unroll
    for (int p = 0; p < 4; ++p)
        dst[(size_t)(n0 + ty + p * 8) * 256 + k0 + tx] = f_to_bf16(tile[tx][ty + p * 8] * sc);
}

// Generic transpose-cast for W1/W2 (z = layer index).
__global__ __launch_bounds__(256) void tcastKN(
    const float* __restrict__ in, unsigned short* __restrict__ out,
    int K, int N, long inStride, long outStride)
{
    in  += (size_t)blockIdx.z * inStride;
    out += (size_t)blockIdx.z * outStride;
    __shared__ float tile[32][33];
    const int t = threadIdx.x, tx = t & 31, ty = t >> 5;
    const int n0 = blockIdx.x * 32, k0 = blockIdx.y * 32;
#pragma unroll
    for (int p = 0; p < 4; ++p)
        tile[ty + p * 8][tx] = in[(size_t)(k0 + ty + p * 8) * N + n0 + tx];
    __syncthreads();
#pragma unroll
    for (int p = 0; p < 4; ++p)
        out[(size_t)(n0 + ty + p * 8) * K + k0 + tx] = f_to_bf16(tile[tx][ty + p * 8]);
}

// ---------------------------------------------------------------------------
__global__ __launch_bounds__(256) void embed_proj_kernel(
    const int* __restrict__ tok, const float* __restrict__ embed,
    const float* __restrict__ W_in, const float* __restrict__ b_in,
    float* __restrict__ x, unsigned short* __restrict__ xh)
{
    __shared__ float emb[8][304];
    __shared__ int tloc[8];
    const int t = threadIdx.x;
    const int r0 = blockIdx.x * 8;
    if (t < 8) tloc[t] = tok[r0 + t];
    __syncthreads();
    for (int i = t; i < 8 * 300; i += 256) {
        int r = i / 300, e = i - r * 300;
        emb[r][e] = embed[(size_t)tloc[r] * 300 + e];
    }
    __syncthreads();
    float acc[8] = {0.f,0.f,0.f,0.f,0.f,0.f,0.f,0.f};
    const int d = t;
    for (int e = 0; e < 300; ++e) {
        float w = W_in[e * 256 + d];
#pragma unroll
        for (int r = 0; r < 8; ++r) acc[r] += emb[r][e] * w;
    }
    const float bb = b_in[d];
#pragma unroll
    for (int r = 0; r < 8; ++r) {
        float o = acc[r] + bb;
        o = o > 0.f ? o : 0.f;
        x[(size_t)(r0 + r) * 256 + d] = o;
        xh[(size_t)(r0 + r) * 256 + d] = f_to_bf16(o);
    }
}

// ---------------------------------------------------------------------------
// bf16 GEMM, 64x64 tile, dbuf BK=32. A bf16 [M][K], WT bf16 [Nc][K].
__global__ __launch_bounds__(256) void gemm_bf16_64(
    const unsigned short* __restrict__ A, const unsigned short* __restrict__ WT,
    const float* __restrict__ bias, float* __restrict__ Cf, unsigned short* __restrict__ Ch,
    int M, int K, int Nc, int relu)
{
    __shared__ unsigned short As[2][64][40];
    __shared__ unsigned short Bs[2][64][40];
    const int t = threadIdx.x;
    const int lane = t & 63, w = t >> 6;
    const int g = lane >> 4, li = lane & 15;
    const int r0 = blockIdx.y * 64, c0 = blockIdx.x * 64;

    f32x4 acc[4];
#pragma unroll
    for (int i = 0; i < 4; ++i) acc[i] = (f32x4){0.f,0.f,0.f,0.f};

    const int arow = t >> 2, ad8 = (t & 3) * 8;

    bf16x8 a0 = *(const bf16x8*)(A  + (size_t)(r0 + arow) * K + ad8);
    bf16x8 b0 = *(const bf16x8*)(WT + (size_t)(c0 + arow) * K + ad8);

    const int nk = K >> 5;
    for (int ki = 0; ki < nk; ++ki) {
        const int cur = ki & 1;
        *(bf16x8*)&As[cur][arow][ad8] = a0;
        *(bf16x8*)&Bs[cur][arow][ad8] = b0;
        if (ki + 1 < nk) {
            const int k0 = (ki + 1) * 32;
            a0 = *(const bf16x8*)(A  + (size_t)(r0 + arow) * K + k0 + ad8);
            b0 = *(const bf16x8*)(WT + (size_t)(c0 + arow) * K + k0 + ad8);
        }
        __syncthreads();
        bf16x8 af = *(const bf16x8*)&As[cur][16 * w + li][g * 8];
#pragma unroll
        for (int sub = 0; sub < 4; ++sub) {
            bf16x8 bfr = *(const bf16x8*)&Bs[cur][16 * sub + li][g * 8];
            acc[sub] = __builtin_amdgcn_mfma_f32_16x16x32_bf16(af, bfr, acc[sub], 0, 0, 0);
        }
    }
#pragma unroll
    for (int sub = 0; sub < 4; ++sub) {
        int col = c0 + sub * 16 + li;
        float bv = bias ? bias[col] : 0.f;
#pragma unroll
        for (int r = 0; r < 4; ++r) {
            int row = r0 + 16 * w + g * 4 + r;
            float o = acc[sub][r] + bv;
            if (relu) o = fmaxf(o, 0.f);
            if (Ch) Ch[(size_t)row * Nc + col] = f_to_bf16(o);
            else    Cf[(size_t)row * Nc + col] = o;
        }
    }
}

// ---------------------------------------------------------------------------
// bf16 GEMM, 32x64 tile (N=256 GEMMs): doubles grid for occupancy.
__global__ __launch_bounds__(256) void gemm_bf16_32(
    const unsigned short* __restrict__ A, const unsigned short* __restrict__ WT,
    const float* __restrict__ bias, float* __restrict__ Cf, unsigned short* __restrict__ Ch,
    int M, int K, int Nc, int relu)
{
    __shared__ unsigned short As[2][32][40];
    __shared__ unsigned short Bs[2][64][40];
    const int t = threadIdx.x;
    const int lane = t & 63, w = t >> 6;
    const int g = lane >> 4, li = lane & 15;
    const int r0 = blockIdx.y * 32, c0 = blockIdx.x * 64;

    f32x4 acc[2];
    acc[0] = (f32x4){0.f,0.f,0.f,0.f};
    acc[1] = (f32x4){0.f,0.f,0.f,0.f};

    const int arow = t >> 3, a4 = (t & 7) * 4;
    const int bcol = t >> 2, bk8 = (t & 3) * 8;

    u16x4 a0 = *(const u16x4*)(A + (size_t)(r0 + arow) * K + a4);
    bf16x8 b0 = *(const bf16x8*)(WT + (size_t)(c0 + bcol) * K + bk8);

    const int nk = K >> 5;
    for (int ki = 0; ki < nk; ++ki) {
        const int cur = ki & 1;
        *(u16x4*)&As[cur][arow][a4] = a0;
        *(bf16x8*)&Bs[cur][bcol][bk8] = b0;
        if (ki + 1 < nk) {
            const int k0 = (ki + 1) * 32;
            a0 = *(const u16x4*)(A + (size_t)(r0 + arow) * K + k0 + a4);
            b0 = *(const bf16x8*)(WT + (size_t)(c0 + bcol) * K + k0 + bk8);
        }
        __syncthreads();
        bf16x8 af = *(const bf16x8*)&As[cur][16 * (w & 1) + li][g * 8];
#pragma unroll
        for (int sub = 0; sub < 2; ++sub) {
            bf16x8 bfr = *(const bf16x8*)&Bs[cur][(w >> 1) * 32 + sub * 16 + li][g * 8];
            acc[sub] = __builtin_amdgcn_mfma_f32_16x16x32_bf16(af, bfr, acc[sub], 0, 0, 0);
        }
    }
#pragma unroll
    for (int sub = 0; sub < 2; ++sub) {
        int col = c0 + (w >> 1) * 32 + sub * 16 + li;
        float bv = bias ? bias[col] : 0.f;
#pragma unroll
        for (int r = 0; r < 4; ++r) {
            int row = r0 + 16 * (w & 1) + g * 4 + r;
            float o = acc[sub][r] + bv;
            if (relu) o = fmaxf(o, 0.f);
            if (Ch) Ch[(size_t)row * Nc + col] = f_to_bf16(o);
            else    Cf[(size_t)row * Nc + col] = o;
        }
    }
}

// ---------------------------------------------------------------------------
// Wo GEMM with fused attention combine: A[row][k] = (zp0+zp1) / (sm0+sm1).
// 32x64 tile, K=256, f32 out. Replaces combine_kernel + Wo GEMM.
__global__ __launch_bounds__(256) void gemm_wo(
    const float* __restrict__ zpart, const float* __restrict__ smpart,
    const unsigned short* __restrict__ WT, float* __restrict__ Cf, int Nc)
{
    __shared__ unsigned short As[32][256];
    __shared__ unsigned short Bs[64][256];
    __shared__ float den[32][8];
    char* Ab = (char*)As; char* Bb = (char*)Bs;
    const int t = threadIdx.x;
    const int lane = t & 63, w = t >> 6;
    const int g = lane >> 4, li = lane & 15;
    const int r0 = blockIdx.y * 32, c0 = blockIdx.x * 64;

    {
        int row = t >> 3, h2 = t & 7;
        float s = smpart[(size_t)(r0 + row) * 8 + h2] +
                  smpart[32768 + (size_t)(r0 + row) * 8 + h2];
        den[row][h2] = 1.f / s;
    }
    __syncthreads();
#pragma unroll
    for (int j = 0; j < 4; ++j) {          // A panel 32x256 from zpart, normalized
        int idx = j * 256 + t;
        int row = idx >> 5;
        int k8 = (idx & 31) * 8;
        const float* z0 = zpart + (size_t)(r0 + row) * 256 + k8;
        const float* z1 = z0 + 1048576;
        float4 a0 = *(const float4*)z0, a1 = *(const float4*)(z0 + 4);
        float4 b0 = *(const float4*)z1, b1 = *(const float4*)(z1 + 4);
        float dv = den[row][k8 >> 5];
        a0.x = (a0.x + b0.x) * dv; a0.y = (a0.y + b0.y) * dv;
        a0.z = (a0.z + b0.z) * dv; a0.w = (a0.w + b0.w) * dv;
        a1.x = (a1.x + b1.x) * dv; a1.y = (a1.y + b1.y) * dv;
        a1.z = (a1.z + b1.z) * dv; a1.w = (a1.w + b1.w) * dv;
        int colb = (idx & 31) * 16;
        int sw = row * 512 + (colb ^ ((row & 7) << 4));
        *(bf16x8*)(Ab + sw) = pack8(a0, a1);
    }
#pragma unroll
    for (int j = 0; j < 8; ++j) {          // B panel 64x256
        int idx = j * 256 + t;
        int row = idx >> 5;
        int colb = (idx & 31) * 16;
        int sw = row * 512 + (colb ^ ((row & 7) << 4));
        *(bf16x8*)(Bb + sw) = *(const bf16x8*)(WT + (size_t)(c0 + row) * 256 + (idx & 31) * 8);
    }
    __syncthreads();
    f32x4 acc[2];
    acc[0] = (f32x4){0.f,0.f,0.f,0.f};
    acc[1] = (f32x4){0.f,0.f,0.f,0.f};
    const int arow = 16 * (w & 1) + li;
    const int xr = (li & 7) << 4;
#pragma unroll
    for (int ks = 0; ks < 8; ++ks) {
        const int kb = (g * 8 + ks * 32) * 2;
        bf16x8 af = *(const bf16x8*)(Ab + arow * 512 + (kb ^ xr));
#pragma unroll
        for (int sub = 0; sub < 2; ++sub) {
            const int brow = (w >> 1) * 32 + sub * 16 + li;
            bf16x8 bfr = *(const bf16x8*)(Bb + brow * 512 + (kb ^ xr));
            acc[sub] = __builtin_amdgcn_mfma_f32_16x16x32_bf16(af, bfr, acc[sub], 0, 0, 0);
        }
    }
#pragma unroll
    for (int sub = 0; sub < 2; ++sub) {
        int col = c0 + (w >> 1) * 32 + sub * 16 + li;
#pragma unroll
        for (int r = 0; r < 4; ++r) {
            int row = r0 + 16 * (w & 1) + g * 4 + r;
            Cf[(size_t)row * Nc + col] = acc[sub][r];
        }
    }
}

// ---------------------------------------------------------------------------
// qrk[b,h,n,rel] = q_n . relk[rel]  (q pre-scaled in Wq cast). Block=(chunk,h,b).
__global__ __launch_bounds__(256) void qrk_kernel(
    const unsigned short* __restrict__ qkvh, const float* __restrict__ relk_g,
    unsigned short* __restrict__ qrkg)
{
    const int n0 = blockIdx.x * 64, h = blockIdx.y, b = blockIdx.z;
    const int t = threadIdx.x, lane = t & 63, w = t >> 6;
    const int g = lane >> 4, li = lane & 15;
    const int qrow = 16 * w + g * 4;

    __shared__ unsigned short relk_s[100][40];
    for (int i = t; i < 400; i += 256) {
        int rr = i >> 2, d8 = (i & 3) * 8;
        const float* sp = relk_g + rr * 32 + d8;
        *(bf16x8*)&relk_s[rr][d8] = pack8(*(const float4*)sp, *(const float4*)(sp + 4));
    }
    bf16x8 qf = *(const bf16x8*)(qkvh + (size_t)(b * NN + n0 + 16 * w + li) * 768 + h * 32 + g * 8);
    __syncthreads();
#pragma unroll
    for (int rc = 0; rc < 7; ++rc) {
        bf16x8 bb = *(const bf16x8*)&relk_s[rc * 16 + li][g * 8];
        f32x4 s = __builtin_amdgcn_mfma_f32_16x16x32_bf16(qf, bb, (f32x4){0.f,0.f,0.f,0.f}, 0, 0, 0);
        int col = rc * 16 + li;
        if (col < 100) {
#pragma unroll
            for (int r = 0; r < 4; ++r)
                qrkg[((size_t)(b * 8 + h) * NN + n0 + qrow + r) * 100 + col] = f_to_bf16(s[r]);
        }
    }
}

// ---------------------------------------------------------------------------
// Attention (best-known r11/r15 variant): 32-q-row chunks, 4 waves =
// 2 q-waves x 2 m-halves, LDS 34.8KB -> 4 blocks/CU.
__global__ __launch_bounds__(256, 4) void attn_mfma(
    const unsigned short* __restrict__ qkvh,  // [4096][768] bf16, q pre-scaled
    const short* __restrict__ rel16,
    const unsigned short* __restrict__ qrkg,  // [64][512][100] bf16
    const float* __restrict__ relv_g,
    float* __restrict__ zpart, float* __restrict__ smpart)
{
    const int p = blockIdx.x;            // 0..1023
    const int cx = p & 7, k = p >> 3;    // k 0..127
    const int sg = cx * 16 + (k >> 3);   // (b, chunk32) slice, XCD-grouped
    const int h  = k & 7;
    const int b = sg >> 4, chunk = sg & 15;
    const int n0 = chunk * 32;

    const int t = threadIdx.x;
    const int lane = t & 63, w = t >> 6;
    const int qw = w & 1, mhalf = w >> 1;
    const int g = lane >> 4, li = lane & 15;
    const int qrow = 16 * qw + g * 4;    // +r, 0..31
    const int mbase = mhalf * 256;

    __shared__ float wrel[32][100];            // 12800 B (shared, atomics)
    __shared__ unsigned short qrk_lds[32][100];// 6400 B
    __shared__ union {
        unsigned short relvT[32][136];         // 8704 B (epilogue)
        struct {
            unsigned short v_t[2][2][32][40];  // [mhalf][buf][d][m] 10240 B
            unsigned short p_s[4][16][40];     // per-wave 5120 B
        } mn;                                  // 15360 B
    } u;                                       // total 34560 B -> 4 blocks/CU

    // prologue: zero wrel, bulk-stage qrk rows (32 x 50 dwords), load Q frag
    for (int i = t; i < 3200; i += 256) ((float*)wrel)[i] = 0.f;
    {
        const unsigned short* qsrc = qrkg + ((size_t)(b * 8 + h) * NN + n0) * 100;
        for (int i = t; i < 1600; i += 256) {
            int row = i / 50, off = (i - row * 50) * 2;
            *(unsigned int*)&qrk_lds[row][off] =
                *(const unsigned int*)(qsrc + (size_t)row * 100 + off);
        }
    }
    bf16x8 qf = *(const bf16x8*)(qkvh + (size_t)(b * NN + n0 + 16 * qw + li) * 768 + h * 32 + g * 8);

    const short* relrow[4];
#pragma unroll
    for (int r = 0; r < 4; ++r)
        relrow[r] = rel16 + ((size_t)b * NN + n0 + qrow + r) * NN;
    const int th = t & 127;
    const int vm = th & 31, vdg = th >> 5;
    const size_t kRB = (size_t)(b * NN) * 768 + 256 + h * 32 + g * 8;
    const size_t vRB = (size_t)(b * NN) * 768 + 512 + h * 32 + vdg * 8;

    bf16x8 kbuf[2][2]; bf16x8 vbuf[2]; short rbuf[2][8];
#pragma unroll
    for (int i = 0; i < 8; ++i)
        rbuf[0][i] = relrow[i & 3][mbase + (i >> 2) * 16 + li];
    kbuf[0][0] = *(const bf16x8*)(qkvh + kRB + (size_t)(mbase + li) * 768);
    kbuf[0][1] = *(const bf16x8*)(qkvh + kRB + (size_t)(mbase + 16 + li) * 768);
    vbuf[0]    = *(const bf16x8*)(qkvh + vRB + (size_t)(mbase + vm) * 768);

    float smacc[4] = {0.f, 0.f, 0.f, 0.f};
    f32x4 zf[2];
    zf[0] = (f32x4){0.f,0.f,0.f,0.f};
    zf[1] = (f32x4){0.f,0.f,0.f,0.f};

    // main loop: 8 tiles of 32 m, one barrier per tile
#pragma unroll
    for (int tt = 0; tt < 8; ++tt) {
        const int cur = tt & 1, nxt = cur ^ 1;
        {   // write own half's V tile transposed [d][m]
            bf16x8 vv = vbuf[cur];
#pragma unroll
            for (int j = 0; j < 8; ++j)
                u.mn.v_t[mhalf][cur][vdg * 8 + j][vm] = (unsigned short)vv[j];
        }
        if (tt + 1 < 8) {
            const int m0n = mbase + (tt + 1) * 32;
#pragma unroll
            for (int i = 0; i < 8; ++i)
                rbuf[nxt][i] = relrow[i & 3][m0n + (i >> 2) * 16 + li];
        }
        __syncthreads();
        bf16x8 kf0 = kbuf[cur][0], kf1 = kbuf[cur][1];
        if (tt + 1 < 8) {   // issue next K/V early (hide under compute)
            const int m0n = mbase + (tt + 1) * 32;
            kbuf[nxt][0] = *(const bf16x8*)(qkvh + kRB + (size_t)(m0n + li) * 768);
            kbuf[nxt][1] = *(const bf16x8*)(qkvh + kRB + (size_t)(m0n + 16 + li) * 768);
            vbuf[nxt]    = *(const bf16x8*)(qkvh + vRB + (size_t)(m0n + vm) * 768);
        }
        f32x4 s0 = __builtin_amdgcn_mfma_f32_16x16x32_bf16(qf, kf0, (f32x4){0.f,0.f,0.f,0.f}, 0, 0, 0);
        f32x4 s1 = __builtin_amdgcn_mfma_f32_16x16x32_bf16(qf, kf1, (f32x4){0.f,0.f,0.f,0.f}, 0, 0, 0);
        float pr[8];
#pragma unroll
        for (int i = 0; i < 8; ++i) {
            const int r = i & 3;
            const int rl = rbuf[cur][i];
            const float qadd = bf16_to_f(qrk_lds[qrow + r][rl < 0 ? 0 : rl]);
            const float sv = ((i >> 2) ? s1[r] : s0[r]) + qadd;
            float pv = 0.f;
            if (rl >= 0) {
                pv = __expf(fminf(sv, 50.f));
                atomicAdd(&wrel[qrow + r][rl], pv);
            }
            smacc[r] += pv;
            pr[i] = pv;
        }
#pragma unroll
        for (int i = 0; i < 8; ++i)
            u.mn.p_s[w][g * 4 + (i & 3)][(i >> 2) * 16 + li] = f_to_bf16(pr[i]);
        asm volatile("s_waitcnt lgkmcnt(0)" ::: "memory");
        __builtin_amdgcn_sched_barrier(0);
        bf16x8 pa = *(const bf16x8*)&u.mn.p_s[w][li][g * 8];
#pragma unroll
        for (int dc = 0; dc < 2; ++dc) {
            bf16x8 vb = *(const bf16x8*)&u.mn.v_t[mhalf][cur][dc * 16 + li][g * 8];
            zf[dc] = __builtin_amdgcn_mfma_f32_16x16x32_bf16(pa, vb, zf[dc], 0, 0, 0);
        }
    }
    __syncthreads();   // wrel atomics + p_s reads complete

    // epilogue: stage relv^T (shared); wrel @ relv added by m-half 0 only
    for (int i = t; i < 32 * 36; i += 256) {
        int d = i / 36, c = 100 + (i - (i / 36) * 36);
        u.relvT[d][c] = 0;
    }
    for (int i = t; i < 400; i += 256) {
        int rr2 = i >> 2, d8 = (i & 3) * 8;
        const float* sp = relv_g + rr2 * 32 + d8;
        float4 s0 = *(const float4*)sp, s1 = *(const float4*)(sp + 4);
        u.relvT[d8 + 0][rr2] = f_to_bf16(s0.x);
        u.relvT[d8 + 1][rr2] = f_to_bf16(s0.y);
        u.relvT[d8 + 2][rr2] = f_to_bf16(s0.z);
        u.relvT[d8 + 3][rr2] = f_to_bf16(s0.w);
        u.relvT[d8 + 4][rr2] = f_to_bf16(s1.x);
        u.relvT[d8 + 5][rr2] = f_to_bf16(s1.y);
        u.relvT[d8 + 6][rr2] = f_to_bf16(s1.z);
        u.relvT[d8 + 7][rr2] = f_to_bf16(s1.w);
    }
    __syncthreads();
    if (mhalf == 0) {
#pragma unroll
        for (int kc = 0; kc < 4; ++kc) {
            const int kbase = kc * 32 + g * 8;
            const float* wp = &wrel[16 * qw + li][0];
            bf16x8 af;
#pragma unroll
            for (int j = 0; j < 8; ++j) {
                int id = kbase + j;
                float val = (id < 100) ? wp[id] : 0.f;
                af[j] = (short)f_to_bf16(val);
            }
#pragma unroll
            for (int dc = 0; dc < 2; ++dc) {
                bf16x8 vbr = *(const bf16x8*)&u.relvT[dc * 16 + li][kbase];
                zf[dc] = __builtin_amdgcn_mfma_f32_16x16x32_bf16(af, vbr, zf[dc], 0, 0, 0);
            }
        }
    }
#pragma unroll
    for (int r = 0; r < 4; ++r) {
        smacc[r] += __shfl_xor(smacc[r], 1, 64);
        smacc[r] += __shfl_xor(smacc[r], 2, 64);
        smacc[r] += __shfl_xor(smacc[r], 4, 64);
        smacc[r] += __shfl_xor(smacc[r], 8, 64);
    }
#pragma unroll
    for (int r = 0; r < 4; ++r) {
        const int row = b * NN + n0 + qrow + r;
        size_t ob = (size_t)mhalf * 1048576 + (size_t)row * 256 + h * 32;
#pragma unroll
        for (int dc = 0; dc < 2; ++dc)
            zpart[ob + dc * 16 + li] = zf[dc][r];
        if (li == 0)
            smpart[(size_t)mhalf * 32768 + (size_t)row * 8 + h] = smacc[r];
    }
}

// ---------------------------------------------------------------------------
__global__ __launch_bounds__(256) void ln_kernel(
    const float* __restrict__ xin, const float* __restrict__ y,
    const float* __restrict__ g, const float* __restrict__ bsh,
    float* __restrict__ xout, unsigned short* __restrict__ xh)
{
    const int t = threadIdx.x;
    const int w = t >> 6, lane = t & 63;
    const size_t row = (size_t)blockIdx.x * 4 + w;
    const float4 xv = *(const float4*)(xin + row * 256 + lane * 4);
    const float4 yv = *(const float4*)(y + row * 256 + lane * 4);
    float4 sv;
    sv.x = xv.x + yv.x; sv.y = xv.y + yv.y; sv.z = xv.z + yv.z; sv.w = xv.w + yv.w;
    float sum = sv.x + sv.y + sv.z + sv.w;
    float sq  = sv.x * sv.x + sv.y * sv.y + sv.z * sv.z + sv.w * sv.w;
#pragma unroll
    for (int off = 1; off < 64; off <<= 1) {
        sum += __shfl_xor(sum, off, 64);
        sq  += __shfl_xor(sq, off, 64);
    }
    const float mu = sum * (1.f / 256.f);
    const float var = sq * (1.f / 256.f) - mu * mu;
    const float rs = rsqrtf(var + 1e-5f);
    const float4 gv = *(const float4*)(g + lane * 4);
    const float4 bv = *(const float4*)(bsh + lane * 4);
    float4 o;
    o.x = (sv.x - mu) * rs * gv.x + bv.x;
    o.y = (sv.y - mu) * rs * gv.y + bv.y;
    o.z = (sv.z - mu) * rs * gv.z + bv.z;
    o.w = (sv.w - mu) * rs * gv.w + bv.w;
    *(float4*)(xout + row * 256 + lane * 4) = o;
    u16x4 oh;
    oh[0] = f_to_bf16(o.x); oh[1] = f_to_bf16(o.y);
    oh[2] = f_to_bf16(o.z); oh[3] = f_to_bf16(o.w);
    *(u16x4*)(xh + row * 256 + lane * 4) = oh;
}

// ---------------------------------------------------------------------------
extern "C" void kernel_launch(void* const* d_in, const int* in_sizes, int n_in,
                              void* d_out, int out_size, void* d_ws, size_t ws_size,
                              hipStream_t stream)
{
    (void)in_sizes; (void)n_in; (void)out_size;
    const int*   tok   = (const int*)d_in[0];
    const int*   rel   = (const int*)d_in[1];
    const void*  mask  = d_in[2];
    const float* embed = (const float*)d_in[3];
    const float* W_in  = (const float*)d_in[4];
    const float* b_in  = (const float*)d_in[5];
    const float* Wq    = (const float*)d_in[6];
    const float* Wk    = (const float*)d_in[7];
    const float* Wv    = (const float*)d_in[8];
    const float* Wo    = (const float*)d_in[9];
    const float* ln1g  = (const float*)d_in[10];
    const float* ln1b  = (const float*)d_in[11];
    const float* ln2g  = (const float*)d_in[12];
    const float* ln2b  = (const float*)d_in[13];
    const float* W1    = (const float*)d_in[14];
    const float* b1    = (const float*)d_in[15];
    const float* W2    = (const float*)d_in[16];
    const float* b2    = (const float*)d_in[17];
    const float* relk  = (const float*)d_in[18];
    const float* relv  = (const float*)d_in[19];
    const float* Wout  = (const float*)d_in[20];
    const float* bout  = (const float*)d_in[21];
    float* out = (float*)d_out;
    const float scale = 0.17677669529663687f;

    float* ws = (float*)d_ws;
    float*          x     = ws;                                   // 1M f32
    unsigned short* xh    = (unsigned short*)(ws + 1048576);      // 0.5M
    float*          zo    = ws + 2097152;                         // 1M
    unsigned short* qkvh  = (unsigned short*)(ws + 3145728);      // 1.5M
    unsigned short* hbh   = (unsigned short*)(ws + 4718592);      // 2M
    float*          zpart = ws + 6815744;                         // 2M
    float*          smpart= ws + 8912896;                         // 64K
    unsigned short* qrkg  = (unsigned short*)(ws + 8978432);      // 1.6384M
    int*            flag  = (int*)(ws + 10616832);
    unsigned short* wt    = (unsigned short*)(ws + 10616848);

    const size_t wsf = ws_size >> 2;
    const bool tierA = wsf >= 13271100;   // all-layer weight cache + dedicated rel16
    short* rel16 = tierA ? (short*)(ws + 12222480) : (short*)hbh;

    detect_mask_kernel<<<1, 256, 0, stream>>>((const unsigned char*)mask, flag);
    embed_proj_kernel<<<512, 256, 0, stream>>>(tok, embed, W_in, b_in, x, xh);
    if (tierA) {
        prep_rel16<<<4096, 256, 0, stream>>>(rel, mask, flag, rel16);
        tcast256<<<dim3(8, 8, 17), 256, 0, stream>>>(Wq, Wk, Wv, Wo, Wout, wt, 4, scale);
        tcastKN<<<dim3(32, 8, 4), 256, 0, stream>>>(W1, wt + 262144, 256, 1024, 262144, 786432);
        tcastKN<<<dim3(8, 32, 4), 256, 0, stream>>>(W2, wt + 524288, 1024, 256, 262144, 786432);
    }

    for (int l = 0; l < 4; ++l) {
        unsigned short* wl = tierA ? wt + (size_t)l * 786432 : wt;
        if (!tierA) {
            prep_rel16<<<4096, 256, 0, stream>>>(rel, mask, flag, rel16);
            tcast256<<<dim3(8, 8, 4), 256, 0, stream>>>(
                Wq + (size_t)l * 65536, Wk + (size_t)l * 65536,
                Wv + (size_t)l * 65536, Wo + (size_t)l * 65536, Wout, wt, 1, scale);
            tcastKN<<<dim3(32, 8, 1), 256, 0, stream>>>(W1 + (size_t)l * 262144, wt + 262144, 256, 1024, 0, 0);
            tcastKN<<<dim3(8, 32, 1), 256, 0, stream>>>(W2 + (size_t)l * 262144, wt + 524288, 1024, 256, 0, 0);
        }
        // fused QKV (q pre-scaled): xh @ WqkvT -> qkvh bf16
        gemm_bf16_64<<<dim3(12, 64), 256, 0, stream>>>(xh, wl, nullptr, nullptr, qkvh,
                                                       NTOK, 256, 768, 0);
        qrk_kernel<<<dim3(8, 8, 8), 256, 0, stream>>>(qkvh, relk, qrkg);
        attn_mfma<<<1024, 256, 0, stream>>>(qkvh, rel16, qrkg, relv, zpart, smpart);
        // Wo GEMM with fused combine/normalize (replaces combine + gemm)
        gemm_wo<<<dim3(4, 128), 256, 0, stream>>>(zpart, smpart, wl + 196608, zo, 256);
        ln_kernel<<<1024, 256, 0, stream>>>(x, zo, ln1g + l * 256, ln1b + l * 256, x, xh);
        gemm_bf16_64<<<dim3(16, 64), 256, 0, stream>>>(xh, wl + 262144, b1 + l * 1024, nullptr, hbh,
                                                       NTOK, 256, 1024, 1);
        gemm_bf16_32<<<dim3(4, 128), 256, 0, stream>>>(hbh, wl + 524288, b2 + l * 256, zo, nullptr,
                                                       NTOK, 1024, 256, 0);
        ln_kernel<<<1024, 256, 0, stream>>>(x, zo, ln2g + l * 256, ln2b + l * 256, x, xh);
    }
    unsigned short* woutT = wt;
    if (tierA) {
        woutT = wt + (size_t)4 * 786432;
    } else {
        tcast256<<<dim3(8, 8, 1), 256, 0, stream>>>(Wq, Wk, Wv, Wo, Wout, wt, 0, scale);
    }
    gemm_bf16_32<<<dim3(4, 128), 256, 0, stream>>>(xh, woutT, bout, out, nullptr,
                                                   NTOK, 256, 256, 0);
}